// Round 2
// baseline (403.302 us; speedup 1.0000x reference)
//
#include <hip/hip_runtime.h>
#include <hip/hip_bf16.h>

// Problem dims (fixed by setup_inputs)
#define BB 128
#define T_ENC 256
#define T_CTX 200
#define E_DIM 256
#define H_DIM 512
#define V_DIM 50000
#define N_OOV 50
#define VEXT  50050
#define FOURH 2048
#define K_GATES 768   // E + H
#define LOGP_SZ (BB * VEXT)          // 6406400
#define OUT_H1_OFF LOGP_SZ
#define OUT_C1_OFF (LOGP_SZ + BB * H_DIM)
#define VCHUNK 2048
#define NCHUNK 25     // 25*2048 = 51200 >= VEXT
#define NBIG 782      // ceil(50000/64)
#define MSP_PITCH 784 // padded 782

typedef __bf16 bf16x8 __attribute__((ext_vector_type(8)));
typedef float  floatx4 __attribute__((ext_vector_type(4)));
typedef float  floatx2 __attribute__((ext_vector_type(2)));

__device__ __forceinline__ float wave_sum(float v) {
#pragma unroll
  for (int m = 32; m > 0; m >>= 1) v += __shfl_xor(v, m, 64);
  return v;
}

__device__ __forceinline__ float sigm(float x) { return 1.0f / (1.0f + __expf(-x)); }

// pack 2 fp32 -> packed bf16x2 (RNE)
__device__ __forceinline__ unsigned f2bf2(float a, float b) {
  unsigned ua = __float_as_uint(a), ub = __float_as_uint(b);
  ua = (ua + 0x7FFFu + ((ua >> 16) & 1u)) >> 16;
  ub = (ub + 0x7FFFu + ((ub >> 16) & 1u)) & 0xFFFF0000u;
  return ua | ub;
}

__device__ __forceinline__ bf16x8 u4bf(uint4 u) {
  union { uint4 a; bf16x8 b; } x; x.a = u; return x.b;
}

// fp32 x8 -> bf16x8 (RNE via hardware cvt; compiler pairs into v_cvt_pk_bf16_f32)
__device__ __forceinline__ bf16x8 cvt8(float4 lo, float4 hi) {
  bf16x8 r;
  r[0] = (__bf16)lo.x; r[1] = (__bf16)lo.y; r[2] = (__bf16)lo.z; r[3] = (__bf16)lo.w;
  r[4] = (__bf16)hi.x; r[5] = (__bf16)hi.y; r[6] = (__bf16)hi.z; r[7] = (__bf16)hi.w;
  return r;
}

// ---------------- prep: weights->bf16 + A matrix, one launch ----------------
__global__ __launch_bounds__(256) void prep_all(
    const float* __restrict__ W_ih, const float* __restrict__ W_hh,
    const float* __restrict__ attnW, const float* __restrict__ cattnW,
    const float* __restrict__ attnb, const float* __restrict__ cattnb,
    const int* __restrict__ input, const float* __restrict__ embT,
    const float* __restrict__ h0,
    __bf16* __restrict__ Wcat, __bf16* __restrict__ Wattn, float* __restrict__ attnbc,
    __bf16* __restrict__ Abuf, float* __restrict__ embf) {
  int n = blockIdx.x, tid = threadIdx.x;
  if (n < 2048) {
    unsigned* wr = (unsigned*)(Wcat + (size_t)n * K_GATES);
    for (int idx = tid; idx < 384; idx += 256) {
      int e0 = idx * 2;
      float2 x = (e0 < 256) ? *(const float2*)(W_ih + (size_t)n * E_DIM + e0)
                            : *(const float2*)(W_hh + (size_t)n * H_DIM + e0 - 256);
      wr[idx] = f2bf2(x.x, x.y);
    }
    if (n < 1024) {
      const float* src = (n < 512) ? (attnW + (size_t)n * H_DIM) : (cattnW + (size_t)(n - 512) * H_DIM);
      unsigned* wa = (unsigned*)(Wattn + (size_t)n * H_DIM);
      float2 x = *(const float2*)(src + tid * 2);
      wa[tid] = f2bf2(x.x, x.y);
    }
    if (n < 4) {
      int i = n * 256 + tid;
      attnbc[i] = (i < 512) ? attnb[i] : cattnb[i - 512];
    }
  } else {
    int b = n - 2048;
    int tok = input[b];
    unsigned* ar = (unsigned*)(Abuf + (size_t)b * K_GATES);
    for (int idx = tid; idx < 384; idx += 256) {
      int e0 = idx * 2;
      float2 x;
      if (e0 < 256) {
        x = *(const float2*)(embT + (size_t)tok * E_DIM + e0);
        *(float2*)(embf + b * E_DIM + e0) = x;
      } else {
        x = *(const float2*)(h0 + (size_t)b * H_DIM + e0 - 256);
      }
      ar[idx] = f2bf2(x.x, x.y);
    }
  }
}

// ---------------- GEMM body (LDS lockstep) — still used by gates_gemm ----------------
template <int BF32, int STATS>
__device__ __forceinline__ void gemm64_body(
    __bf16 (* __restrict__ As)[72], __bf16 (* __restrict__ Bs)[72],
    const __bf16* __restrict__ Abf, const void* __restrict__ Bsrc,
    const float* __restrict__ bias, float* __restrict__ C,
    int n0, int N, int Koff, int Klen, int Kpitch, size_t ldc,
    float2* __restrict__ mspart, int cb) {
  int tid = threadIdx.x, lane = tid & 63, wid = tid >> 6;

  floatx4 acc[2][4];
#pragma unroll
  for (int i = 0; i < 2; i++)
#pragma unroll
    for (int j = 0; j < 4; j++) acc[i][j] = (floatx4){0.f, 0.f, 0.f, 0.f};

  int arow = tid >> 1, ahalf = tid & 1;   // A: 128 rows x 64 bf16, 64 B/thread
  int brow = tid >> 2, bq = tid & 3;      // B: 64 rows x 64, 16 elems/thread
  int gnb = n0 + brow; if (gnb > N - 1) gnb = N - 1;

  const __bf16* abase = Abf + (size_t)arow * Kpitch + Koff + ahalf * 32;
  const float*  bfb = (const float*)Bsrc + (size_t)gnb * Kpitch + Koff + bq * 16;
  const __bf16* bhb = (const __bf16*)Bsrc + (size_t)gnb * Kpitch + Koff + bq * 16;

  uint4 ra[4];
  float4 rbf[4];
  uint4 rbh[2];
  {
    const uint4* s = (const uint4*)abase;
    ra[0] = s[0]; ra[1] = s[1]; ra[2] = s[2]; ra[3] = s[3];
    if (BF32) { const float4* t = (const float4*)bfb; rbf[0] = t[0]; rbf[1] = t[1]; rbf[2] = t[2]; rbf[3] = t[3]; }
    else      { const uint4* t = (const uint4*)bhb;  rbh[0] = t[0]; rbh[1] = t[1]; }
  }

  for (int k0 = 0; k0 < Klen; k0 += 64) {
    __syncthreads();
    { uint4* d = (uint4*)&As[arow][ahalf * 32]; d[0] = ra[0]; d[1] = ra[1]; d[2] = ra[2]; d[3] = ra[3]; }
    if (BF32) {
      uint4 o0, o1;
      o0.x = f2bf2(rbf[0].x, rbf[0].y); o0.y = f2bf2(rbf[0].z, rbf[0].w);
      o0.z = f2bf2(rbf[1].x, rbf[1].y); o0.w = f2bf2(rbf[1].z, rbf[1].w);
      o1.x = f2bf2(rbf[2].x, rbf[2].y); o1.y = f2bf2(rbf[2].z, rbf[2].w);
      o1.z = f2bf2(rbf[3].x, rbf[3].y); o1.w = f2bf2(rbf[3].z, rbf[3].w);
      uint4* d = (uint4*)&Bs[brow][bq * 16]; d[0] = o0; d[1] = o1;
    } else {
      uint4* d = (uint4*)&Bs[brow][bq * 16]; d[0] = rbh[0]; d[1] = rbh[1];
    }
    if (k0 + 64 < Klen) {
      const uint4* s = (const uint4*)(abase + k0 + 64);
      ra[0] = s[0]; ra[1] = s[1]; ra[2] = s[2]; ra[3] = s[3];
      if (BF32) { const float4* t = (const float4*)(bfb + k0 + 64); rbf[0] = t[0]; rbf[1] = t[1]; rbf[2] = t[2]; rbf[3] = t[3]; }
      else      { const uint4* t = (const uint4*)(bhb + k0 + 64);  rbh[0] = t[0]; rbh[1] = t[1]; }
    }
    __syncthreads();
#pragma unroll
    for (int kk = 0; kk < 64; kk += 32) {
      int kbase = kk + (lane >> 4) * 8;
      bf16x8 a0 = *(const bf16x8*)&As[wid * 32 + (lane & 15)][kbase];
      bf16x8 a1 = *(const bf16x8*)&As[wid * 32 + 16 + (lane & 15)][kbase];
      bf16x8 bfr[4];
#pragma unroll
      for (int j = 0; j < 4; j++) bfr[j] = *(const bf16x8*)&Bs[j * 16 + (lane & 15)][kbase];
#pragma unroll
      for (int j = 0; j < 4; j++) {
        acc[0][j] = __builtin_amdgcn_mfma_f32_16x16x32_bf16(a0, bfr[j], acc[0][j], 0, 0, 0);
        acc[1][j] = __builtin_amdgcn_mfma_f32_16x16x32_bf16(a1, bfr[j], acc[1][j], 0, 0, 0);
      }
    }
  }
  // C/D layout: col=lane&15, row=(lane>>4)*4+r  [m89/m91]
  int cn = lane & 15, cq = lane >> 4;
#pragma unroll
  for (int i = 0; i < 2; i++)
#pragma unroll
    for (int j = 0; j < 4; j++)
#pragma unroll
      for (int r = 0; r < 4; r++) {
        int row = wid * 32 + i * 16 + cq * 4 + r;
        int col = n0 + j * 16 + cn;
        if (col < N) {
          float v = acc[i][j][r];
          if (bias) v += bias[col];
          C[(size_t)row * ldc + col] = v;
        }
      }
  if (STATS) {
#pragma unroll
    for (int i = 0; i < 2; i++)
#pragma unroll
      for (int r = 0; r < 4; r++) {
        int row = wid * 32 + i * 16 + cq * 4 + r;
        float v[4]; float mx = -1e30f;
#pragma unroll
        for (int j = 0; j < 4; j++) {
          int col = n0 + j * 16 + cn;
          float x = acc[i][j][r] + bias[col < N ? col : N - 1];
          v[j] = (col < N) ? x : -1e30f;
          mx = fmaxf(mx, v[j]);
        }
#pragma unroll
        for (int mk = 1; mk <= 8; mk <<= 1) mx = fmaxf(mx, __shfl_xor(mx, mk, 64));
        float s = 0.f;
#pragma unroll
        for (int j = 0; j < 4; j++) s += (v[j] > -1e29f) ? __expf(v[j] - mx) : 0.f;
#pragma unroll
        for (int mk = 1; mk <= 8; mk <<= 1) s += __shfl_xor(s, mk, 64);
        if (cn == 0) mspart[(size_t)row * MSP_PITCH + cb] = make_float2(mx, s);
      }
  }
}

// gates GEMM, split-K x2: blocks [kh*32 + nb]
__global__ __launch_bounds__(256) void gates_gemm(
    const __bf16* __restrict__ Abuf, const __bf16* __restrict__ Wcat,
    float* __restrict__ g0, float* __restrict__ g1) {
  __shared__ __bf16 As[128][72];
  __shared__ __bf16 Bs[64][72];
  int bx = blockIdx.x;
  int kh = bx >> 5, nb = bx & 31;
  gemm64_body<0, 0>(As, Bs, Abuf, Wcat, nullptr, kh ? g1 : g0, nb * 64, FOURH,
                    kh * 384, 384, K_GATES, FOURH, nullptr, 0);
}

// ---------------- mega_gemm: barrier-free wave-streaming GEMM ----------------
// Per block: 128x64 C-tile, K=512. Each wave owns 16 columns x all 128 rows.
// B (outW rows; the 102 MB HBM stream) is loaded straight from global into
// MFMA B-fragment layout (lane: col=l&15, k=(l>>4)*8+j -> 32 B contiguous),
// read exactly once per block. A (h1b, 128 KB, L2-resident) is loaded
// per-wave redundantly (L1/L2 absorbs). Double-buffered register pipeline,
// ZERO barriers in the K-loop. Epilogue: acc -> padded LDS tile -> one
// barrier -> full 256 B/row coalesced stores + fused per-row softmax
// partials (mspart layout identical to before; final_kernel unchanged).
// Plain (cached) stores on logits: they're re-read by final_kernel and fit L3.
__global__ __launch_bounds__(256) void mega_gemm(
    const __bf16* __restrict__ h1b, const float* __restrict__ outW,
    const float* __restrict__ outb, float* __restrict__ logits, size_t lpitch,
    const __bf16* __restrict__ Wattn, const float* __restrict__ attnbc,
    float* __restrict__ decbuf, float2* __restrict__ mspart) {
  __shared__ float ctile[128][68];   // pad 68: float4-aligned rows, ~2-way banks
  int bx = blockIdx.x;
  int tid = threadIdx.x, lane = tid & 63, wid = tid >> 6;
  int cn = lane & 15, kq = lane >> 4;
  const int big = bx < NBIG;
  int n0 = big ? bx * 64 : (bx - NBIG) * 64;
  int mycol = n0 + wid * 16 + cn;

  // A fragment base: row=cn (+i*16), k = kq*8 (+slab*32)
  const __bf16* a0 = h1b + (size_t)cn * H_DIM + kq * 8;

  floatx4 acc[8];
#pragma unroll
  for (int i = 0; i < 8; ++i) acc[i] = (floatx4){0.f, 0.f, 0.f, 0.f};

  if (big) {
    int gn = mycol < V_DIM ? mycol : V_DIM - 1;   // clamp (dup loads on last block)
    const float* bp = outW + (size_t)gn * H_DIM + kq * 8;
    uint4  ra[2][8];
    float4 rb[2][2];
#pragma unroll
    for (int i = 0; i < 8; ++i) ra[0][i] = *(const uint4*)(a0 + i * 16 * H_DIM);
    rb[0][0] = *(const float4*)bp;
    rb[0][1] = *(const float4*)(bp + 4);
#pragma unroll
    for (int s = 0; s < 16; ++s) {
      const int cur = s & 1, nxt = cur ^ 1;
      if (s < 15) {
        int ko = (s + 1) * 32;
#pragma unroll
        for (int i = 0; i < 8; ++i) ra[nxt][i] = *(const uint4*)(a0 + i * 16 * H_DIM + ko);
        rb[nxt][0] = *(const float4*)(bp + ko);
        rb[nxt][1] = *(const float4*)(bp + ko + 4);
      }
      bf16x8 bv = cvt8(rb[cur][0], rb[cur][1]);
#pragma unroll
      for (int i = 0; i < 8; ++i)
        acc[i] = __builtin_amdgcn_mfma_f32_16x16x32_bf16(u4bf(ra[cur][i]), bv, acc[i], 0, 0, 0);
    }
    float bcol = outb[gn];
#pragma unroll
    for (int i = 0; i < 8; ++i)
#pragma unroll
      for (int r = 0; r < 4; ++r)
        ctile[i * 16 + kq * 4 + r][wid * 16 + cn] = acc[i][r] + bcol;
  } else {
    const __bf16* bp = Wattn + (size_t)mycol * H_DIM + kq * 8;
    uint4 ra[2][8];
    uint4 rbh[2];
#pragma unroll
    for (int i = 0; i < 8; ++i) ra[0][i] = *(const uint4*)(a0 + i * 16 * H_DIM);
    rbh[0] = *(const uint4*)bp;
#pragma unroll
    for (int s = 0; s < 16; ++s) {
      const int cur = s & 1, nxt = cur ^ 1;
      if (s < 15) {
        int ko = (s + 1) * 32;
#pragma unroll
        for (int i = 0; i < 8; ++i) ra[nxt][i] = *(const uint4*)(a0 + i * 16 * H_DIM + ko);
        rbh[nxt] = *(const uint4*)(bp + ko);
      }
      bf16x8 bv = u4bf(rbh[cur]);
#pragma unroll
      for (int i = 0; i < 8; ++i)
        acc[i] = __builtin_amdgcn_mfma_f32_16x16x32_bf16(u4bf(ra[cur][i]), bv, acc[i], 0, 0, 0);
    }
    float bcol = attnbc[mycol];
#pragma unroll
    for (int i = 0; i < 8; ++i)
#pragma unroll
      for (int r = 0; r < 4; ++r)
        ctile[i * 16 + kq * 4 + r][wid * 16 + cn] = acc[i][r] + bcol;
  }
  __syncthreads();

  // Epilogue: 16 lanes hold a full 64-col row -> coalesced store + row stats.
  int rr = tid >> 4, c16 = tid & 15;
  if (big) {
#pragma unroll
    for (int p = 0; p < 8; ++p) {
      int row = p * 16 + rr;
      int c4 = c16 * 4;
      int col = n0 + c4;
      floatx4 v = *(const floatx4*)&ctile[row][c4];
      // softmax partials over this block's valid cols
      float v0 = (col + 0 < V_DIM) ? v[0] : -1e30f;
      float v1 = (col + 1 < V_DIM) ? v[1] : -1e30f;
      float v2 = (col + 2 < V_DIM) ? v[2] : -1e30f;
      float v3 = (col + 3 < V_DIM) ? v[3] : -1e30f;
      float mx = fmaxf(fmaxf(v0, v1), fmaxf(v2, v3));
#pragma unroll
      for (int mk = 1; mk <= 8; mk <<= 1) mx = fmaxf(mx, __shfl_xor(mx, mk, 64));
      float sum = __expf(v0 - mx) + __expf(v1 - mx) + __expf(v2 - mx) + __expf(v3 - mx);
#pragma unroll
      for (int mk = 1; mk <= 8; mk <<= 1) sum += __shfl_xor(sum, mk, 64);
      if (c16 == 0) mspart[(size_t)row * MSP_PITCH + bx] = make_float2(mx, sum);
      if (col + 4 <= V_DIM) {
        float* dst = logits + (size_t)row * lpitch + col;
        if ((lpitch & 3) == 0) {
          *(floatx4*)dst = v;
        } else {
          *(floatx2*)dst = (floatx2){v[0], v[1]};
          *(floatx2*)(dst + 2) = (floatx2){v[2], v[3]};
        }
      }
    }
  } else {
#pragma unroll
    for (int p = 0; p < 8; ++p) {
      int row = p * 16 + rr;
      floatx4 v = *(const floatx4*)&ctile[row][c16 * 4];
      *(floatx4*)(decbuf + (size_t)row * 1024 + n0 + c16 * 4) = v;
    }
  }
}

// ---------------- LSTM elementwise (sums the two split-K halves) ----------------
__global__ __launch_bounds__(256) void lstm_kernel(
    const float* __restrict__ gA, const float* __restrict__ gB,
    const float* __restrict__ b_ih, const float* __restrict__ b_hh,
    const float* __restrict__ c0,
    float* __restrict__ h1_out, float* __restrict__ c1_out, __bf16* __restrict__ h1b) {
  int idx = blockIdx.x * 256 + threadIdx.x;
  int b = idx >> 9, j = idx & 511;
  const float* ga = gA + b * FOURH;
  const float* gb = gB + b * FOURH;
  float iv = ga[j]        + gb[j]        + b_ih[j]        + b_hh[j];
  float fv = ga[512 + j]  + gb[512 + j]  + b_ih[512 + j]  + b_hh[512 + j];
  float gv = ga[1024 + j] + gb[1024 + j] + b_ih[1024 + j] + b_hh[1024 + j];
  float ov = ga[1536 + j] + gb[1536 + j] + b_ih[1536 + j] + b_hh[1536 + j];
  float c1 = sigm(fv) * c0[idx] + sigm(iv) * tanhf(gv);
  float h1 = sigm(ov) * tanhf(c1);
  h1_out[idx] = h1;
  c1_out[idx] = c1;
  h1b[idx] = (__bf16)h1;
}

// ---------------- flash attention (1024 blocks) ----------------
__global__ __launch_bounds__(256) void flash_kernel(
    const float* __restrict__ enc, const float* __restrict__ cenc,
    const float* __restrict__ decbuf, float* __restrict__ opart,
    float2* __restrict__ mlb, float* __restrict__ rawsc) {
  __shared__ float so[4][512];
  __shared__ float sml[4][2];
  int g = blockIdx.x;
  int b = g & 127;
  int cc = g >> 7;               // 0..7
  int which = cc >> 2, chunk = cc & 3;
  int tchunk = which ? 50 : 64;
  int t0 = chunk * tchunk;
  const float* src = which ? (cenc + (size_t)b * T_CTX * H_DIM) : (enc + (size_t)b * T_ENC * H_DIM);
  const float* decp = decbuf + b * 1024 + which * 512;
  int tid = threadIdx.x, lane = tid & 63, wid = tid >> 6;
  float4 d0 = *(const float4*)(decp + lane * 8);
  float4 d1 = *(const float4*)(decp + lane * 8 + 4);
  float m = -1e30f, l = 0.f;
  float4 o0 = {0.f, 0.f, 0.f, 0.f}, o1 = {0.f, 0.f, 0.f, 0.f};
  for (int t = t0 + wid; t < t0 + tchunk; t += 4) {
    const float* row = src + (size_t)t * H_DIM + lane * 8;
    float4 r0 = *(const float4*)row;
    float4 r1 = *(const float4*)(row + 4);
    float p = r0.x * d0.x + r0.y * d0.y + r0.z * d0.z + r0.w * d0.w +
              r1.x * d1.x + r1.y * d1.y + r1.z * d1.z + r1.w * d1.w;
    p = wave_sum(p);
    if (which && lane == 0) rawsc[b * T_CTX + t] = p;
    float mn = fmaxf(m, p);
    float sc = __expf(m - mn);
    float e  = __expf(p - mn);
    l = l * sc + e;
    o0.x = o0.x * sc + e * r0.x; o0.y = o0.y * sc + e * r0.y;
    o0.z = o0.z * sc + e * r0.z; o0.w = o0.w * sc + e * r0.w;
    o1.x = o1.x * sc + e * r1.x; o1.y = o1.y * sc + e * r1.y;
    o1.z = o1.z * sc + e * r1.z; o1.w = o1.w * sc + e * r1.w;
    m = mn;
  }
  *(float4*)&so[wid][lane * 8]     = o0;
  *(float4*)&so[wid][lane * 8 + 4] = o1;
  if (lane == 0) { sml[wid][0] = m; sml[wid][1] = l; }
  __syncthreads();
  float M = fmaxf(fmaxf(sml[0][0], sml[1][0]), fmaxf(sml[2][0], sml[3][0]));
  float w0 = __expf(sml[0][0] - M), w1 = __expf(sml[1][0] - M);
  float w2 = __expf(sml[2][0] - M), w3 = __expf(sml[3][0] - M);
  float L = w0 * sml[0][1] + w1 * sml[1][1] + w2 * sml[2][1] + w3 * sml[3][1];
  int h = tid, h2 = tid + 256;
  float O0 = w0 * so[0][h]  + w1 * so[1][h]  + w2 * so[2][h]  + w3 * so[3][h];
  float O1 = w0 * so[0][h2] + w1 * so[1][h2] + w2 * so[2][h2] + w3 * so[3][h2];
  opart[(size_t)g * 512 + h]  = O0;
  opart[(size_t)g * 512 + h2] = O1;
  if (tid == 0) mlb[g] = make_float2(M, L);
}

// ---------------- final: combine everything + write logp ----------------
__global__ __launch_bounds__(256) void final_kernel(
    const float* __restrict__ logits, size_t lpitch,
    float* __restrict__ out, const int* __restrict__ ctx_inp,
    const float* __restrict__ rawsc, const float2* __restrict__ mlb,
    const float2* __restrict__ mspart, const float* __restrict__ opart,
    const float* __restrict__ h1f, const float* __restrict__ embf,
    const float* __restrict__ genW, const float* __restrict__ genb,
    const float* __restrict__ sigb) {
  __shared__ float pc[VCHUNK];
  __shared__ float sm[256], ss[256];
  __shared__ float red8[8];
  int bx = blockIdx.x;           // c*128 + b
  int b = bx & 127, c = bx >> 7;
  int tid = threadIdx.x, lane = tid & 63, wid = tid >> 6;
  int cidx = (tid < T_CTX) ? ctx_inp[b * T_CTX + tid] : 0;

  // attention chunk-combine weights
  float2 e0 = mlb[b], e1 = mlb[128 + b], e2 = mlb[256 + b], e3 = mlb[384 + b];        // which=0
  float2 f0 = mlb[512 + b], f1 = mlb[640 + b], f2 = mlb[768 + b], f3 = mlb[896 + b];  // which=1
  float M0 = fmaxf(fmaxf(e0.x, e1.x), fmaxf(e2.x, e3.x));
  float a0 = __expf(e0.x - M0), a1 = __expf(e1.x - M0), a2 = __expf(e2.x - M0), a3 = __expf(e3.x - M0);
  float L0 = a0 * e0.y + a1 * e1.y + a2 * e2.y + a3 * e3.y;
  float M1 = fmaxf(fmaxf(f0.x, f1.x), fmaxf(f2.x, f3.x));
  float c0_ = __expf(f0.x - M1), c1_ = __expf(f1.x - M1), c2_ = __expf(f2.x - M1), c3_ = __expf(f3.x - M1);
  float L1 = c0_ * f0.y + c1_ * f1.y + c2_ * f2.y + c3_ * f3.y;

  // p_gen dot: feats = [ctx, cctx, h1, emb] . genW
  float acc = 0.f;
  for (int j = tid; j < 1792; j += 256) {
    float x;
    if (j < 1024) {
      int which = j >> 9, h = j & 511;
      const float* op = opart + ((size_t)(which * 512 + b) * 512) + h;
      if (which == 0)
        x = (a0 * op[0] + a1 * op[128 * 512] + a2 * op[256 * 512] + a3 * op[384 * 512]) / L0;
      else
        x = (c0_ * op[0] + c1_ * op[128 * 512] + c2_ * op[256 * 512] + c3_ * op[384 * 512]) / L1;
    } else if (j < 1536) x = h1f[b * 512 + j - 1024];
    else x = embf[b * 256 + j - 1536];
    acc += x * genW[j];
  }
  float cnt = (tid < T_CTX && cidx > 0) ? 1.f : 0.f;
  acc = wave_sum(acc); cnt = wave_sum(cnt);
  if (lane == 0) { red8[wid] = acc; red8[4 + wid] = cnt; }

  // row softmax stats from 782 per-block partials
  float m = -1e30f, s = 0.f;
  for (int cb = tid; cb < NBIG; cb += 256) {
    float2 p = mspart[(size_t)b * MSP_PITCH + cb];
    float mo = fmaxf(m, p.x);
    s = s * __expf(m - mo) + p.y * __expf(p.x - mo);
    m = mo;
  }
  sm[tid] = m; ss[tid] = s;
#pragma unroll
  for (int k = 0; k < 8; k++) pc[tid * 8 + k] = 0.f;
  __syncthreads();
  for (int st = 128; st; st >>= 1) {
    if (tid < st) {
      float m2 = sm[tid + st], s2 = ss[tid + st];
      float mo = fmaxf(sm[tid], m2);
      ss[tid] = ss[tid] * __expf(sm[tid] - mo) + s2 * __expf(m2 - mo);
      sm[tid] = mo;
    }
    __syncthreads();
  }
  float rm = sm[0], rs = ss[0];
  float pg;
  {
    float a = red8[0] + red8[1] + red8[2] + red8[3];
    float cn = red8[4] + red8[5] + red8[6] + red8[7];
    pg = sigm(a + genb[0] + sigb[0]);
    if (cn == 0.f) pg = 1.0f;
  }
  int v0c = c * VCHUNK;
  if (tid < T_CTX) {
    int rel = cidx - v0c;
    if (rel >= 0 && rel < VCHUNK) {
      float val = __expf(rawsc[b * T_CTX + tid] - M1) / L1;
      atomicAdd(&pc[rel], val);
    }
  }
  __syncthreads();
  float inv = 1.0f / rs, pc1 = 1.0f - pg;
  const float* rowsrc = logits + (size_t)b * lpitch;
  float* rowdst = out + (size_t)b * VEXT;
  int li0 = tid * 8;
#pragma unroll
  for (int k = 0; k < 4; k++) {
    int li = li0 + 2 * k;
    int v = v0c + li;
    float2 x = *(const float2*)(rowsrc + v);   // in-bounds of buffer; garbage past V_DIM guarded below
    float pv0 = (v < V_DIM)     ? __expf(x.x - rm) * inv : 0.f;
    float pv1 = (v + 1 < V_DIM) ? __expf(x.y - rm) * inv : 0.f;
    float r0 = __logf(fmaxf(pg * pv0 + pc1 * pc[li],     1e-10f));
    float r1 = __logf(fmaxf(pg * pv1 + pc1 * pc[li + 1], 1e-10f));
    if (v + 1 < VEXT)      *(float2*)(rowdst + v) = make_float2(r0, r1);
    else if (v < VEXT)     rowdst[v] = r0;
  }
}

extern "C" void kernel_launch(void* const* d_in, const int* in_sizes, int n_in,
                              void* d_out, int out_size, void* d_ws, size_t ws_size,
                              hipStream_t stream) {
  const int*   input   = (const int*)d_in[0];
  const float* h0      = (const float*)d_in[1];
  const float* c0      = (const float*)d_in[2];
  const float* enc     = (const float*)d_in[3];
  const float* cenc    = (const float*)d_in[4];
  const int*   ctx_inp = (const int*)d_in[5];
  const float* embT    = (const float*)d_in[6];
  const float* W_ih    = (const float*)d_in[7];
  const float* W_hh    = (const float*)d_in[8];
  const float* b_ih    = (const float*)d_in[9];
  const float* b_hh    = (const float*)d_in[10];
  const float* attnW   = (const float*)d_in[11];
  const float* attnb   = (const float*)d_in[12];
  const float* cattnW  = (const float*)d_in[13];
  const float* cattnb  = (const float*)d_in[14];
  const float* genW    = (const float*)d_in[15];
  const float* genb    = (const float*)d_in[16];
  const float* sigb    = (const float*)d_in[17];
  const float* outW    = (const float*)d_in[18];
  const float* outb    = (const float*)d_in[19];

  char* ws = (char*)d_ws;
  __bf16* Wcat   = (__bf16*)(ws + 0);            // 3145728
  __bf16* Wattn  = (__bf16*)(ws + 3145728);      // 1048576 -> 4194304
  float*  attnbc = (float*)(ws + 4194304);       // 4096    -> 4198400
  __bf16* Abuf   = (__bf16*)(ws + 4198400);      // 196608  -> 4395008
  float*  embf   = (float*)(ws + 4395008);       // 131072  -> 4526080
  float*  gates  = (float*)(ws + 4526080);       // 1048576 -> 5574656
  float*  gates2 = (float*)(ws + 5574656);       // 1048576 -> 6623232
  __bf16* h1b    = (__bf16*)(ws + 6623232);      // 131072  -> 6754304
  float*  decbuf = (float*)(ws + 6754304);       // 524288  -> 7278592
  float*  opart  = (float*)(ws + 7278592);       // 2097152 -> 9375744
  float2* mlb    = (float2*)(ws + 9375744);      // 8192    -> 9383936
  float*  rawsc  = (float*)(ws + 9383936);       // 102400  -> 9486336
  float2* mspart = (float2*)(ws + 9486336);      // 128*784*8 = 802816 -> 10289152
  const size_t logits_off = 10289152;
  const size_t LPITCH_AL = 50176;                // 64B-aligned row pitch

  float* outF = (float*)d_out;
  bool padded = ws_size >= logits_off + (size_t)BB * LPITCH_AL * 4;
  float* logits = padded ? (float*)(ws + logits_off) : outF;
  size_t lpitch = padded ? LPITCH_AL : (size_t)VEXT;

  float* h1_out = outF + OUT_H1_OFF;
  float* c1_out = outF + OUT_C1_OFF;

  prep_all<<<2176, 256, 0, stream>>>(W_ih, W_hh, attnW, cattnW, attnb, cattnb,
                                     input, embT, h0, Wcat, Wattn, attnbc, Abuf, embf);
  gates_gemm<<<64, 256, 0, stream>>>(Abuf, Wcat, gates, gates2);
  lstm_kernel<<<256, 256, 0, stream>>>(gates, gates2, b_ih, b_hh, c0, h1_out, c1_out, h1b);
  mega_gemm<<<NBIG + 16, 256, 0, stream>>>(h1b, outW, outb, logits, lpitch,
                                           Wattn, attnbc, decbuf, mspart);
  flash_kernel<<<1024, 256, 0, stream>>>(enc, cenc, decbuf, opart, mlb, rawsc);
  final_kernel<<<NCHUNK * 128, 256, 0, stream>>>(logits, lpitch, outF, ctx_inp, rawsc, mlb,
                                                 mspart, opart, h1_out, embf, genW, genb, sigb);
}

// Round 3
// 402.388 us; speedup vs baseline: 1.0023x; 1.0023x over previous
//
#include <hip/hip_runtime.h>
#include <hip/hip_bf16.h>

// Problem dims (fixed by setup_inputs)
#define BB 128
#define T_ENC 256
#define T_CTX 200
#define E_DIM 256
#define H_DIM 512
#define V_DIM 50000
#define N_OOV 50
#define VEXT  50050
#define FOURH 2048
#define K_GATES 768   // E + H
#define LOGP_SZ (BB * VEXT)          // 6406400
#define OUT_H1_OFF LOGP_SZ
#define OUT_C1_OFF (LOGP_SZ + BB * H_DIM)
#define VCHUNK 2048
#define NCHUNK 25     // 25*2048 = 51200 >= VEXT
#define NBIG 782      // ceil(50000/64)
#define MSP_PITCH 784 // padded 782

typedef __bf16 bf16x8 __attribute__((ext_vector_type(8)));
typedef float  floatx4 __attribute__((ext_vector_type(4)));
typedef float  floatx2 __attribute__((ext_vector_type(2)));

// counted vmem wait + scheduler fence (pins the software pipeline; rule #18)
#define WAITV(N) { asm volatile("s_waitcnt vmcnt(" #N ")" ::: "memory"); __builtin_amdgcn_sched_barrier(0); }

__device__ __forceinline__ float wave_sum(float v) {
#pragma unroll
  for (int m = 32; m > 0; m >>= 1) v += __shfl_xor(v, m, 64);
  return v;
}

__device__ __forceinline__ float sigm(float x) { return 1.0f / (1.0f + __expf(-x)); }

// pack 2 fp32 -> packed bf16x2 (RNE)
__device__ __forceinline__ unsigned f2bf2(float a, float b) {
  unsigned ua = __float_as_uint(a), ub = __float_as_uint(b);
  ua = (ua + 0x7FFFu + ((ua >> 16) & 1u)) >> 16;
  ub = (ub + 0x7FFFu + ((ub >> 16) & 1u)) & 0xFFFF0000u;
  return ua | ub;
}

__device__ __forceinline__ bf16x8 u4bf(uint4 u) {
  union { uint4 a; bf16x8 b; } x; x.a = u; return x.b;
}

// fp32 x8 -> bf16x8 (RNE via hardware cvt; compiler pairs into v_cvt_pk_bf16_f32)
__device__ __forceinline__ bf16x8 cvt8(float4 lo, float4 hi) {
  bf16x8 r;
  r[0] = (__bf16)lo.x; r[1] = (__bf16)lo.y; r[2] = (__bf16)lo.z; r[3] = (__bf16)lo.w;
  r[4] = (__bf16)hi.x; r[5] = (__bf16)hi.y; r[6] = (__bf16)hi.z; r[7] = (__bf16)hi.w;
  return r;
}

// ---------------- prep: weights->bf16 + A matrix, one launch ----------------
__global__ __launch_bounds__(256) void prep_all(
    const float* __restrict__ W_ih, const float* __restrict__ W_hh,
    const float* __restrict__ attnW, const float* __restrict__ cattnW,
    const float* __restrict__ attnb, const float* __restrict__ cattnb,
    const int* __restrict__ input, const float* __restrict__ embT,
    const float* __restrict__ h0,
    __bf16* __restrict__ Wcat, __bf16* __restrict__ Wattn, float* __restrict__ attnbc,
    __bf16* __restrict__ Abuf, float* __restrict__ embf) {
  int n = blockIdx.x, tid = threadIdx.x;
  if (n < 2048) {
    unsigned* wr = (unsigned*)(Wcat + (size_t)n * K_GATES);
    for (int idx = tid; idx < 384; idx += 256) {
      int e0 = idx * 2;
      float2 x = (e0 < 256) ? *(const float2*)(W_ih + (size_t)n * E_DIM + e0)
                            : *(const float2*)(W_hh + (size_t)n * H_DIM + e0 - 256);
      wr[idx] = f2bf2(x.x, x.y);
    }
    if (n < 1024) {
      const float* src = (n < 512) ? (attnW + (size_t)n * H_DIM) : (cattnW + (size_t)(n - 512) * H_DIM);
      unsigned* wa = (unsigned*)(Wattn + (size_t)n * H_DIM);
      float2 x = *(const float2*)(src + tid * 2);
      wa[tid] = f2bf2(x.x, x.y);
    }
    if (n < 4) {
      int i = n * 256 + tid;
      attnbc[i] = (i < 512) ? attnb[i] : cattnb[i - 512];
    }
  } else {
    int b = n - 2048;
    int tok = input[b];
    unsigned* ar = (unsigned*)(Abuf + (size_t)b * K_GATES);
    for (int idx = tid; idx < 384; idx += 256) {
      int e0 = idx * 2;
      float2 x;
      if (e0 < 256) {
        x = *(const float2*)(embT + (size_t)tok * E_DIM + e0);
        *(float2*)(embf + b * E_DIM + e0) = x;
      } else {
        x = *(const float2*)(h0 + (size_t)b * H_DIM + e0 - 256);
      }
      ar[idx] = f2bf2(x.x, x.y);
    }
  }
}

// ---------------- GEMM body (LDS lockstep) — still used by gates_gemm ----------------
template <int BF32, int STATS>
__device__ __forceinline__ void gemm64_body(
    __bf16 (* __restrict__ As)[72], __bf16 (* __restrict__ Bs)[72],
    const __bf16* __restrict__ Abf, const void* __restrict__ Bsrc,
    const float* __restrict__ bias, float* __restrict__ C,
    int n0, int N, int Koff, int Klen, int Kpitch, size_t ldc,
    float2* __restrict__ mspart, int cb) {
  int tid = threadIdx.x, lane = tid & 63, wid = tid >> 6;

  floatx4 acc[2][4];
#pragma unroll
  for (int i = 0; i < 2; i++)
#pragma unroll
    for (int j = 0; j < 4; j++) acc[i][j] = (floatx4){0.f, 0.f, 0.f, 0.f};

  int arow = tid >> 1, ahalf = tid & 1;   // A: 128 rows x 64 bf16, 64 B/thread
  int brow = tid >> 2, bq = tid & 3;      // B: 64 rows x 64, 16 elems/thread
  int gnb = n0 + brow; if (gnb > N - 1) gnb = N - 1;

  const __bf16* abase = Abf + (size_t)arow * Kpitch + Koff + ahalf * 32;
  const float*  bfb = (const float*)Bsrc + (size_t)gnb * Kpitch + Koff + bq * 16;
  const __bf16* bhb = (const __bf16*)Bsrc + (size_t)gnb * Kpitch + Koff + bq * 16;

  uint4 ra[4];
  float4 rbf[4];
  uint4 rbh[2];
  {
    const uint4* s = (const uint4*)abase;
    ra[0] = s[0]; ra[1] = s[1]; ra[2] = s[2]; ra[3] = s[3];
    if (BF32) { const float4* t = (const float4*)bfb; rbf[0] = t[0]; rbf[1] = t[1]; rbf[2] = t[2]; rbf[3] = t[3]; }
    else      { const uint4* t = (const uint4*)bhb;  rbh[0] = t[0]; rbh[1] = t[1]; }
  }

  for (int k0 = 0; k0 < Klen; k0 += 64) {
    __syncthreads();
    { uint4* d = (uint4*)&As[arow][ahalf * 32]; d[0] = ra[0]; d[1] = ra[1]; d[2] = ra[2]; d[3] = ra[3]; }
    if (BF32) {
      uint4 o0, o1;
      o0.x = f2bf2(rbf[0].x, rbf[0].y); o0.y = f2bf2(rbf[0].z, rbf[0].w);
      o0.z = f2bf2(rbf[1].x, rbf[1].y); o0.w = f2bf2(rbf[1].z, rbf[1].w);
      o1.x = f2bf2(rbf[2].x, rbf[2].y); o1.y = f2bf2(rbf[2].z, rbf[2].w);
      o1.z = f2bf2(rbf[3].x, rbf[3].y); o1.w = f2bf2(rbf[3].z, rbf[3].w);
      uint4* d = (uint4*)&Bs[brow][bq * 16]; d[0] = o0; d[1] = o1;
    } else {
      uint4* d = (uint4*)&Bs[brow][bq * 16]; d[0] = rbh[0]; d[1] = rbh[1];
    }
    if (k0 + 64 < Klen) {
      const uint4* s = (const uint4*)(abase + k0 + 64);
      ra[0] = s[0]; ra[1] = s[1]; ra[2] = s[2]; ra[3] = s[3];
      if (BF32) { const float4* t = (const float4*)(bfb + k0 + 64); rbf[0] = t[0]; rbf[1] = t[1]; rbf[2] = t[2]; rbf[3] = t[3]; }
      else      { const uint4* t = (const uint4*)(bhb + k0 + 64);  rbh[0] = t[0]; rbh[1] = t[1]; }
    }
    __syncthreads();
#pragma unroll
    for (int kk = 0; kk < 64; kk += 32) {
      int kbase = kk + (lane >> 4) * 8;
      bf16x8 a0 = *(const bf16x8*)&As[wid * 32 + (lane & 15)][kbase];
      bf16x8 a1 = *(const bf16x8*)&As[wid * 32 + 16 + (lane & 15)][kbase];
      bf16x8 bfr[4];
#pragma unroll
      for (int j = 0; j < 4; j++) bfr[j] = *(const bf16x8*)&Bs[j * 16 + (lane & 15)][kbase];
#pragma unroll
      for (int j = 0; j < 4; j++) {
        acc[0][j] = __builtin_amdgcn_mfma_f32_16x16x32_bf16(a0, bfr[j], acc[0][j], 0, 0, 0);
        acc[1][j] = __builtin_amdgcn_mfma_f32_16x16x32_bf16(a1, bfr[j], acc[1][j], 0, 0, 0);
      }
    }
  }
  // C/D layout: col=lane&15, row=(lane>>4)*4+r  [m89/m91]
  int cn = lane & 15, cq = lane >> 4;
#pragma unroll
  for (int i = 0; i < 2; i++)
#pragma unroll
    for (int j = 0; j < 4; j++)
#pragma unroll
      for (int r = 0; r < 4; r++) {
        int row = wid * 32 + i * 16 + cq * 4 + r;
        int col = n0 + j * 16 + cn;
        if (col < N) {
          float v = acc[i][j][r];
          if (bias) v += bias[col];
          C[(size_t)row * ldc + col] = v;
        }
      }
  if (STATS) {
#pragma unroll
    for (int i = 0; i < 2; i++)
#pragma unroll
      for (int r = 0; r < 4; r++) {
        int row = wid * 32 + i * 16 + cq * 4 + r;
        float v[4]; float mx = -1e30f;
#pragma unroll
        for (int j = 0; j < 4; j++) {
          int col = n0 + j * 16 + cn;
          float x = acc[i][j][r] + bias[col < N ? col : N - 1];
          v[j] = (col < N) ? x : -1e30f;
          mx = fmaxf(mx, v[j]);
        }
#pragma unroll
        for (int mk = 1; mk <= 8; mk <<= 1) mx = fmaxf(mx, __shfl_xor(mx, mk, 64));
        float s = 0.f;
#pragma unroll
        for (int j = 0; j < 4; j++) s += (v[j] > -1e29f) ? __expf(v[j] - mx) : 0.f;
#pragma unroll
        for (int mk = 1; mk <= 8; mk <<= 1) s += __shfl_xor(s, mk, 64);
        if (cn == 0) mspart[(size_t)row * MSP_PITCH + cb] = make_float2(mx, s);
      }
  }
}

// gates GEMM, split-K x2: blocks [kh*32 + nb]
__global__ __launch_bounds__(256) void gates_gemm(
    const __bf16* __restrict__ Abuf, const __bf16* __restrict__ Wcat,
    float* __restrict__ g0, float* __restrict__ g1) {
  __shared__ __bf16 As[128][72];
  __shared__ __bf16 Bs[64][72];
  int bx = blockIdx.x;
  int kh = bx >> 5, nb = bx & 31;
  gemm64_body<0, 0>(As, Bs, Abuf, Wcat, nullptr, kh ? g1 : g0, nb * 64, FOURH,
                    kh * 384, 384, K_GATES, FOURH, nullptr, 0);
}

// ---------------- mega_gemm: wave-streaming GEMM, asm-pinned pipeline ----------------
// Per block: 128x64 C-tile, K=512 (16 slabs of 32). Each wave owns 16 cols x 128 rows.
// B (outW, HBM stream) register-prefetched 4 slabs deep; A (h1b, L2-resident) 2 deep.
// Load issue is placed AFTER the consuming MFMA cluster (buffer reuse), and the
// schedule is pinned with counted s_waitcnt vmcnt(N) + sched_barrier(0) each slab.
// Issue order/iter: [WAIT][compute s][issue A(s+2) x8][issue B(s+4) x2]
// => ops younger than A(s): B(s+2),A(s+1),B(s+3) = 12 -> steady-state vmcnt(12);
// prologue/tail: s0:6, s1:14, s13:10, s14:8, s15:0 (derived in journal).
// __launch_bounds__(256,3): budget ~170 VGPR so the pipeline state stays live
// (R2's 76-VGPR build collapsed the double-buffer -> latency-bound 93us).
__global__ __launch_bounds__(256, 3) void mega_gemm(
    const __bf16* __restrict__ h1b, const float* __restrict__ outW,
    const float* __restrict__ outb, float* __restrict__ logits, size_t lpitch,
    const __bf16* __restrict__ Wattn, const float* __restrict__ attnbc,
    float* __restrict__ decbuf, float2* __restrict__ mspart) {
  __shared__ float ctile[128][68];   // pad 68: float4-aligned rows, ~2-way banks
  int bx = blockIdx.x;
  int tid = threadIdx.x, lane = tid & 63, wid = tid >> 6;
  int cn = lane & 15, kq = lane >> 4;
  const int big = bx < NBIG;
  int n0 = big ? bx * 64 : (bx - NBIG) * 64;
  int mycol = n0 + wid * 16 + cn;

  // A fragment base: row=cn (+i*16), k = kq*8 (+slab*32)
  const __bf16* a0 = h1b + (size_t)cn * H_DIM + kq * 8;

  floatx4 acc[8];
#pragma unroll
  for (int i = 0; i < 8; ++i) acc[i] = (floatx4){0.f, 0.f, 0.f, 0.f};

  if (big) {
    int gn = mycol < V_DIM ? mycol : V_DIM - 1;   // clamp (dup loads on last block)
    const float* bp = outW + (size_t)gn * H_DIM + kq * 8;
    uint4  ra[2][8];   // A: 2 slabs in flight
    float4 rb[4][2];   // B: 4 slabs in flight
    // prologue: A(0),A(1), B(0..3)  -> 24 vmem ops outstanding
#pragma unroll
    for (int i = 0; i < 8; ++i) ra[0][i] = *(const uint4*)(a0 + i * 16 * H_DIM);
#pragma unroll
    for (int i = 0; i < 8; ++i) ra[1][i] = *(const uint4*)(a0 + i * 16 * H_DIM + 32);
#pragma unroll
    for (int t = 0; t < 4; ++t) {
      rb[t][0] = *(const float4*)(bp + t * 32);
      rb[t][1] = *(const float4*)(bp + t * 32 + 4);
    }
#pragma unroll
    for (int s = 0; s < 16; ++s) {
      if (s == 0)       WAITV(6)
      else if (s == 1)  WAITV(14)
      else if (s == 13) WAITV(10)
      else if (s == 14) WAITV(8)
      else if (s == 15) WAITV(0)
      else              WAITV(12)
      bf16x8 bv = cvt8(rb[s & 3][0], rb[s & 3][1]);
#pragma unroll
      for (int i = 0; i < 8; ++i)
        acc[i] = __builtin_amdgcn_mfma_f32_16x16x32_bf16(u4bf(ra[s & 1][i]), bv, acc[i], 0, 0, 0);
      if (s + 2 < 16) {
        int ko = (s + 2) * 32;
#pragma unroll
        for (int i = 0; i < 8; ++i) ra[s & 1][i] = *(const uint4*)(a0 + i * 16 * H_DIM + ko);
      }
      if (s + 4 < 16) {
        int ko = (s + 4) * 32;
        rb[s & 3][0] = *(const float4*)(bp + ko);
        rb[s & 3][1] = *(const float4*)(bp + ko + 4);
      }
    }
    float bcol = outb[gn];
#pragma unroll
    for (int i = 0; i < 8; ++i)
#pragma unroll
      for (int r = 0; r < 4; ++r)
        ctile[i * 16 + kq * 4 + r][wid * 16 + cn] = acc[i][r] + bcol;
  } else {
    const __bf16* bp = Wattn + (size_t)mycol * H_DIM + kq * 8;
    uint4 ra[2][8];
    uint4 rbh[2];
#pragma unroll
    for (int i = 0; i < 8; ++i) ra[0][i] = *(const uint4*)(a0 + i * 16 * H_DIM);
    rbh[0] = *(const uint4*)bp;
#pragma unroll
    for (int s = 0; s < 16; ++s) {
      const int cur = s & 1, nxt = cur ^ 1;
      if (s < 15) {
        int ko = (s + 1) * 32;
#pragma unroll
        for (int i = 0; i < 8; ++i) ra[nxt][i] = *(const uint4*)(a0 + i * 16 * H_DIM + ko);
        rbh[nxt] = *(const uint4*)(bp + ko);
      }
      bf16x8 bv = u4bf(rbh[cur]);
#pragma unroll
      for (int i = 0; i < 8; ++i)
        acc[i] = __builtin_amdgcn_mfma_f32_16x16x32_bf16(u4bf(ra[cur][i]), bv, acc[i], 0, 0, 0);
    }
    float bcol = attnbc[mycol];
#pragma unroll
    for (int i = 0; i < 8; ++i)
#pragma unroll
      for (int r = 0; r < 4; ++r)
        ctile[i * 16 + kq * 4 + r][wid * 16 + cn] = acc[i][r] + bcol;
  }
  __syncthreads();

  // Epilogue: 16 lanes hold a full 64-col row -> coalesced store + row stats.
  int rr = tid >> 4, c16 = tid & 15;
  if (big) {
#pragma unroll
    for (int p = 0; p < 8; ++p) {
      int row = p * 16 + rr;
      int c4 = c16 * 4;
      int col = n0 + c4;
      floatx4 v = *(const floatx4*)&ctile[row][c4];
      // softmax partials over this block's valid cols
      float v0 = (col + 0 < V_DIM) ? v[0] : -1e30f;
      float v1 = (col + 1 < V_DIM) ? v[1] : -1e30f;
      float v2 = (col + 2 < V_DIM) ? v[2] : -1e30f;
      float v3 = (col + 3 < V_DIM) ? v[3] : -1e30f;
      float mx = fmaxf(fmaxf(v0, v1), fmaxf(v2, v3));
#pragma unroll
      for (int mk = 1; mk <= 8; mk <<= 1) mx = fmaxf(mx, __shfl_xor(mx, mk, 64));
      float sum = __expf(v0 - mx) + __expf(v1 - mx) + __expf(v2 - mx) + __expf(v3 - mx);
#pragma unroll
      for (int mk = 1; mk <= 8; mk <<= 1) sum += __shfl_xor(sum, mk, 64);
      if (c16 == 0) mspart[(size_t)row * MSP_PITCH + bx] = make_float2(mx, sum);
      if (col + 4 <= V_DIM) {
        float* dst = logits + (size_t)row * lpitch + col;
        if ((lpitch & 3) == 0) {
          *(floatx4*)dst = v;
        } else {
          *(floatx2*)dst = (floatx2){v[0], v[1]};
          *(floatx2*)(dst + 2) = (floatx2){v[2], v[3]};
        }
      }
    }
  } else {
#pragma unroll
    for (int p = 0; p < 8; ++p) {
      int row = p * 16 + rr;
      floatx4 v = *(const floatx4*)&ctile[row][c16 * 4];
      *(floatx4*)(decbuf + (size_t)row * 1024 + n0 + c16 * 4) = v;
    }
  }
}

// ---------------- LSTM elementwise (sums the two split-K halves) ----------------
__global__ __launch_bounds__(256) void lstm_kernel(
    const float* __restrict__ gA, const float* __restrict__ gB,
    const float* __restrict__ b_ih, const float* __restrict__ b_hh,
    const float* __restrict__ c0,
    float* __restrict__ h1_out, float* __restrict__ c1_out, __bf16* __restrict__ h1b) {
  int idx = blockIdx.x * 256 + threadIdx.x;
  int b = idx >> 9, j = idx & 511;
  const float* ga = gA + b * FOURH;
  const float* gb = gB + b * FOURH;
  float iv = ga[j]        + gb[j]        + b_ih[j]        + b_hh[j];
  float fv = ga[512 + j]  + gb[512 + j]  + b_ih[512 + j]  + b_hh[512 + j];
  float gv = ga[1024 + j] + gb[1024 + j] + b_ih[1024 + j] + b_hh[1024 + j];
  float ov = ga[1536 + j] + gb[1536 + j] + b_ih[1536 + j] + b_hh[1536 + j];
  float c1 = sigm(fv) * c0[idx] + sigm(iv) * tanhf(gv);
  float h1 = sigm(ov) * tanhf(c1);
  h1_out[idx] = h1;
  c1_out[idx] = c1;
  h1b[idx] = (__bf16)h1;
}

// ---------------- flash attention (1024 blocks) ----------------
__global__ __launch_bounds__(256) void flash_kernel(
    const float* __restrict__ enc, const float* __restrict__ cenc,
    const float* __restrict__ decbuf, float* __restrict__ opart,
    float2* __restrict__ mlb, float* __restrict__ rawsc) {
  __shared__ float so[4][512];
  __shared__ float sml[4][2];
  int g = blockIdx.x;
  int b = g & 127;
  int cc = g >> 7;               // 0..7
  int which = cc >> 2, chunk = cc & 3;
  int tchunk = which ? 50 : 64;
  int t0 = chunk * tchunk;
  const float* src = which ? (cenc + (size_t)b * T_CTX * H_DIM) : (enc + (size_t)b * T_ENC * H_DIM);
  const float* decp = decbuf + b * 1024 + which * 512;
  int tid = threadIdx.x, lane = tid & 63, wid = tid >> 6;
  float4 d0 = *(const float4*)(decp + lane * 8);
  float4 d1 = *(const float4*)(decp + lane * 8 + 4);
  float m = -1e30f, l = 0.f;
  float4 o0 = {0.f, 0.f, 0.f, 0.f}, o1 = {0.f, 0.f, 0.f, 0.f};
  for (int t = t0 + wid; t < t0 + tchunk; t += 4) {
    const float* row = src + (size_t)t * H_DIM + lane * 8;
    float4 r0 = *(const float4*)row;
    float4 r1 = *(const float4*)(row + 4);
    float p = r0.x * d0.x + r0.y * d0.y + r0.z * d0.z + r0.w * d0.w +
              r1.x * d1.x + r1.y * d1.y + r1.z * d1.z + r1.w * d1.w;
    p = wave_sum(p);
    if (which && lane == 0) rawsc[b * T_CTX + t] = p;
    float mn = fmaxf(m, p);
    float sc = __expf(m - mn);
    float e  = __expf(p - mn);
    l = l * sc + e;
    o0.x = o0.x * sc + e * r0.x; o0.y = o0.y * sc + e * r0.y;
    o0.z = o0.z * sc + e * r0.z; o0.w = o0.w * sc + e * r0.w;
    o1.x = o1.x * sc + e * r1.x; o1.y = o1.y * sc + e * r1.y;
    o1.z = o1.z * sc + e * r1.z; o1.w = o1.w * sc + e * r1.w;
    m = mn;
  }
  *(float4*)&so[wid][lane * 8]     = o0;
  *(float4*)&so[wid][lane * 8 + 4] = o1;
  if (lane == 0) { sml[wid][0] = m; sml[wid][1] = l; }
  __syncthreads();
  float M = fmaxf(fmaxf(sml[0][0], sml[1][0]), fmaxf(sml[2][0], sml[3][0]));
  float w0 = __expf(sml[0][0] - M), w1 = __expf(sml[1][0] - M);
  float w2 = __expf(sml[2][0] - M), w3 = __expf(sml[3][0] - M);
  float L = w0 * sml[0][1] + w1 * sml[1][1] + w2 * sml[2][1] + w3 * sml[3][1];
  int h = tid, h2 = tid + 256;
  float O0 = w0 * so[0][h]  + w1 * so[1][h]  + w2 * so[2][h]  + w3 * so[3][h];
  float O1 = w0 * so[0][h2] + w1 * so[1][h2] + w2 * so[2][h2] + w3 * so[3][h2];
  opart[(size_t)g * 512 + h]  = O0;
  opart[(size_t)g * 512 + h2] = O1;
  if (tid == 0) mlb[g] = make_float2(M, L);
}

// ---------------- final: combine everything + write logp ----------------
__global__ __launch_bounds__(256) void final_kernel(
    const float* __restrict__ logits, size_t lpitch,
    float* __restrict__ out, const int* __restrict__ ctx_inp,
    const float* __restrict__ rawsc, const float2* __restrict__ mlb,
    const float2* __restrict__ mspart, const float* __restrict__ opart,
    const float* __restrict__ h1f, const float* __restrict__ embf,
    const float* __restrict__ genW, const float* __restrict__ genb,
    const float* __restrict__ sigb) {
  __shared__ float pc[VCHUNK];
  __shared__ float sm[256], ss[256];
  __shared__ float red8[8];
  int bx = blockIdx.x;           // c*128 + b
  int b = bx & 127, c = bx >> 7;
  int tid = threadIdx.x, lane = tid & 63, wid = tid >> 6;
  int cidx = (tid < T_CTX) ? ctx_inp[b * T_CTX + tid] : 0;

  // attention chunk-combine weights
  float2 e0 = mlb[b], e1 = mlb[128 + b], e2 = mlb[256 + b], e3 = mlb[384 + b];        // which=0
  float2 f0 = mlb[512 + b], f1 = mlb[640 + b], f2 = mlb[768 + b], f3 = mlb[896 + b];  // which=1
  float M0 = fmaxf(fmaxf(e0.x, e1.x), fmaxf(e2.x, e3.x));
  float a0 = __expf(e0.x - M0), a1 = __expf(e1.x - M0), a2 = __expf(e2.x - M0), a3 = __expf(e3.x - M0);
  float L0 = a0 * e0.y + a1 * e1.y + a2 * e2.y + a3 * e3.y;
  float M1 = fmaxf(fmaxf(f0.x, f1.x), fmaxf(f2.x, f3.x));
  float c0_ = __expf(f0.x - M1), c1_ = __expf(f1.x - M1), c2_ = __expf(f2.x - M1), c3_ = __expf(f3.x - M1);
  float L1 = c0_ * f0.y + c1_ * f1.y + c2_ * f2.y + c3_ * f3.y;

  // p_gen dot: feats = [ctx, cctx, h1, emb] . genW
  float acc = 0.f;
  for (int j = tid; j < 1792; j += 256) {
    float x;
    if (j < 1024) {
      int which = j >> 9, h = j & 511;
      const float* op = opart + ((size_t)(which * 512 + b) * 512) + h;
      if (which == 0)
        x = (a0 * op[0] + a1 * op[128 * 512] + a2 * op[256 * 512] + a3 * op[384 * 512]) / L0;
      else
        x = (c0_ * op[0] + c1_ * op[128 * 512] + c2_ * op[256 * 512] + c3_ * op[384 * 512]) / L1;
    } else if (j < 1536) x = h1f[b * 512 + j - 1024];
    else x = embf[b * 256 + j - 1536];
    acc += x * genW[j];
  }
  float cnt = (tid < T_CTX && cidx > 0) ? 1.f : 0.f;
  acc = wave_sum(acc); cnt = wave_sum(cnt);
  if (lane == 0) { red8[wid] = acc; red8[4 + wid] = cnt; }

  // row softmax stats from 782 per-block partials
  float m = -1e30f, s = 0.f;
  for (int cb = tid; cb < NBIG; cb += 256) {
    float2 p = mspart[(size_t)b * MSP_PITCH + cb];
    float mo = fmaxf(m, p.x);
    s = s * __expf(m - mo) + p.y * __expf(p.x - mo);
    m = mo;
  }
  sm[tid] = m; ss[tid] = s;
#pragma unroll
  for (int k = 0; k < 8; k++) pc[tid * 8 + k] = 0.f;
  __syncthreads();
  for (int st = 128; st; st >>= 1) {
    if (tid < st) {
      float m2 = sm[tid + st], s2 = ss[tid + st];
      float mo = fmaxf(sm[tid], m2);
      ss[tid] = ss[tid] * __expf(sm[tid] - mo) + s2 * __expf(m2 - mo);
      sm[tid] = mo;
    }
    __syncthreads();
  }
  float rm = sm[0], rs = ss[0];
  float pg;
  {
    float a = red8[0] + red8[1] + red8[2] + red8[3];
    float cn = red8[4] + red8[5] + red8[6] + red8[7];
    pg = sigm(a + genb[0] + sigb[0]);
    if (cn == 0.f) pg = 1.0f;
  }
  int v0c = c * VCHUNK;
  if (tid < T_CTX) {
    int rel = cidx - v0c;
    if (rel >= 0 && rel < VCHUNK) {
      float val = __expf(rawsc[b * T_CTX + tid] - M1) / L1;
      atomicAdd(&pc[rel], val);
    }
  }
  __syncthreads();
  float inv = 1.0f / rs, pc1 = 1.0f - pg;
  const float* rowsrc = logits + (size_t)b * lpitch;
  float* rowdst = out + (size_t)b * VEXT;
  int li0 = tid * 8;
#pragma unroll
  for (int k = 0; k < 4; k++) {
    int li = li0 + 2 * k;
    int v = v0c + li;
    float2 x = *(const float2*)(rowsrc + v);   // in-bounds of buffer; garbage past V_DIM guarded below
    float pv0 = (v < V_DIM)     ? __expf(x.x - rm) * inv : 0.f;
    float pv1 = (v + 1 < V_DIM) ? __expf(x.y - rm) * inv : 0.f;
    float r0 = __logf(fmaxf(pg * pv0 + pc1 * pc[li],     1e-10f));
    float r1 = __logf(fmaxf(pg * pv1 + pc1 * pc[li + 1], 1e-10f));
    if (v + 1 < VEXT)      *(float2*)(rowdst + v) = make_float2(r0, r1);
    else if (v < VEXT)     rowdst[v] = r0;
  }
}

extern "C" void kernel_launch(void* const* d_in, const int* in_sizes, int n_in,
                              void* d_out, int out_size, void* d_ws, size_t ws_size,
                              hipStream_t stream) {
  const int*   input   = (const int*)d_in[0];
  const float* h0      = (const float*)d_in[1];
  const float* c0      = (const float*)d_in[2];
  const float* enc     = (const float*)d_in[3];
  const float* cenc    = (const float*)d_in[4];
  const int*   ctx_inp = (const int*)d_in[5];
  const float* embT    = (const float*)d_in[6];
  const float* W_ih    = (const float*)d_in[7];
  const float* W_hh    = (const float*)d_in[8];
  const float* b_ih    = (const float*)d_in[9];
  const float* b_hh    = (const float*)d_in[10];
  const float* attnW   = (const float*)d_in[11];
  const float* attnb   = (const float*)d_in[12];
  const float* cattnW  = (const float*)d_in[13];
  const float* cattnb  = (const float*)d_in[14];
  const float* genW    = (const float*)d_in[15];
  const float* genb    = (const float*)d_in[16];
  const float* sigb    = (const float*)d_in[17];
  const float* outW    = (const float*)d_in[18];
  const float* outb    = (const float*)d_in[19];

  char* ws = (char*)d_ws;
  __bf16* Wcat   = (__bf16*)(ws + 0);            // 3145728
  __bf16* Wattn  = (__bf16*)(ws + 3145728);      // 1048576 -> 4194304
  float*  attnbc = (float*)(ws + 4194304);       // 4096    -> 4198400
  __bf16* Abuf   = (__bf16*)(ws + 4198400);      // 196608  -> 4395008
  float*  embf   = (float*)(ws + 4395008);       // 131072  -> 4526080
  float*  gates  = (float*)(ws + 4526080);       // 1048576 -> 5574656
  float*  gates2 = (float*)(ws + 5574656);       // 1048576 -> 6623232
  __bf16* h1b    = (__bf16*)(ws + 6623232);      // 131072  -> 6754304
  float*  decbuf = (float*)(ws + 6754304);       // 524288  -> 7278592
  float*  opart  = (float*)(ws + 7278592);       // 2097152 -> 9375744
  float2* mlb    = (float2*)(ws + 9375744);      // 8192    -> 9383936
  float*  rawsc  = (float*)(ws + 9383936);       // 102400  -> 9486336
  float2* mspart = (float2*)(ws + 9486336);      // 128*784*8 = 802816 -> 10289152
  const size_t logits_off = 10289152;
  const size_t LPITCH_AL = 50176;                // 64B-aligned row pitch

  float* outF = (float*)d_out;
  bool padded = ws_size >= logits_off + (size_t)BB * LPITCH_AL * 4;
  float* logits = padded ? (float*)(ws + logits_off) : outF;
  size_t lpitch = padded ? LPITCH_AL : (size_t)VEXT;

  float* h1_out = outF + OUT_H1_OFF;
  float* c1_out = outF + OUT_C1_OFF;

  prep_all<<<2176, 256, 0, stream>>>(W_ih, W_hh, attnW, cattnW, attnb, cattnb,
                                     input, embT, h0, Wcat, Wattn, attnbc, Abuf, embf);
  gates_gemm<<<64, 256, 0, stream>>>(Abuf, Wcat, gates, gates2);
  lstm_kernel<<<256, 256, 0, stream>>>(gates, gates2, b_ih, b_hh, c0, h1_out, c1_out, h1b);
  mega_gemm<<<NBIG + 16, 256, 0, stream>>>(h1b, outW, outb, logits, lpitch,
                                           Wattn, attnbc, decbuf, mspart);
  flash_kernel<<<1024, 256, 0, stream>>>(enc, cenc, decbuf, opart, mlb, rawsc);
  final_kernel<<<NCHUNK * 128, 256, 0, stream>>>(logits, lpitch, outF, ctx_inp, rawsc, mlb,
                                                 mspart, opart, h1_out, embf, genW, genb, sigb);
}

// Round 4
// 389.271 us; speedup vs baseline: 1.0360x; 1.0337x over previous
//
#include <hip/hip_runtime.h>
#include <hip/hip_bf16.h>

// Problem dims (fixed by setup_inputs)
#define BB 128
#define T_ENC 256
#define T_CTX 200
#define E_DIM 256
#define H_DIM 512
#define V_DIM 50000
#define N_OOV 50
#define VEXT  50050
#define FOURH 2048
#define K_GATES 768   // E + H
#define LOGP_SZ (BB * VEXT)          // 6406400
#define OUT_H1_OFF LOGP_SZ
#define OUT_C1_OFF (LOGP_SZ + BB * H_DIM)
#define VCHUNK 2048
#define NCHUNK 25     // 25*2048 = 51200 >= VEXT
#define NBIG 782      // ceil(50000/64)
#define MSP_PITCH 784 // padded 782

typedef __bf16 bf16x8 __attribute__((ext_vector_type(8)));
typedef float  floatx4 __attribute__((ext_vector_type(4)));
typedef float  floatx2 __attribute__((ext_vector_type(2)));

__device__ __forceinline__ float wave_sum(float v) {
#pragma unroll
  for (int m = 32; m > 0; m >>= 1) v += __shfl_xor(v, m, 64);
  return v;
}

__device__ __forceinline__ float sigm(float x) { return 1.0f / (1.0f + __expf(-x)); }

// pack 2 fp32 -> packed bf16x2 (RNE)
__device__ __forceinline__ unsigned f2bf2(float a, float b) {
  unsigned ua = __float_as_uint(a), ub = __float_as_uint(b);
  ua = (ua + 0x7FFFu + ((ua >> 16) & 1u)) >> 16;
  ub = (ub + 0x7FFFu + ((ub >> 16) & 1u)) & 0xFFFF0000u;
  return ua | ub;
}

// ---------------- prep: weights->bf16 + A matrix, one launch ----------------
__global__ __launch_bounds__(256) void prep_all(
    const float* __restrict__ W_ih, const float* __restrict__ W_hh,
    const float* __restrict__ attnW, const float* __restrict__ cattnW,
    const float* __restrict__ attnb, const float* __restrict__ cattnb,
    const int* __restrict__ input, const float* __restrict__ embT,
    const float* __restrict__ h0,
    __bf16* __restrict__ Wcat, __bf16* __restrict__ Wattn, float* __restrict__ attnbc,
    __bf16* __restrict__ Abuf, float* __restrict__ embf) {
  int n = blockIdx.x, tid = threadIdx.x;
  if (n < 2048) {
    unsigned* wr = (unsigned*)(Wcat + (size_t)n * K_GATES);
    for (int idx = tid; idx < 384; idx += 256) {
      int e0 = idx * 2;
      float2 x = (e0 < 256) ? *(const float2*)(W_ih + (size_t)n * E_DIM + e0)
                            : *(const float2*)(W_hh + (size_t)n * H_DIM + e0 - 256);
      wr[idx] = f2bf2(x.x, x.y);
    }
    if (n < 1024) {
      const float* src = (n < 512) ? (attnW + (size_t)n * H_DIM) : (cattnW + (size_t)(n - 512) * H_DIM);
      unsigned* wa = (unsigned*)(Wattn + (size_t)n * H_DIM);
      float2 x = *(const float2*)(src + tid * 2);
      wa[tid] = f2bf2(x.x, x.y);
    }
    if (n < 4) {
      int i = n * 256 + tid;
      attnbc[i] = (i < 512) ? attnb[i] : cattnb[i - 512];
    }
  } else {
    int b = n - 2048;
    int tok = input[b];
    unsigned* ar = (unsigned*)(Abuf + (size_t)b * K_GATES);
    for (int idx = tid; idx < 384; idx += 256) {
      int e0 = idx * 2;
      float2 x;
      if (e0 < 256) {
        x = *(const float2*)(embT + (size_t)tok * E_DIM + e0);
        *(float2*)(embf + b * E_DIM + e0) = x;
      } else {
        x = *(const float2*)(h0 + (size_t)b * H_DIM + e0 - 256);
      }
      ar[idx] = f2bf2(x.x, x.y);
    }
  }
}

// ---------------- GEMM body (LDS lockstep) — used by gates_gemm + attn path ----------------
template <int BF32, int STATS>
__device__ __forceinline__ void gemm64_body(
    __bf16 (* __restrict__ As)[72], __bf16 (* __restrict__ Bs)[72],
    const __bf16* __restrict__ Abf, const void* __restrict__ Bsrc,
    const float* __restrict__ bias, float* __restrict__ C,
    int n0, int N, int Koff, int Klen, int Kpitch, size_t ldc,
    float2* __restrict__ mspart, int cb) {
  int tid = threadIdx.x, lane = tid & 63, wid = tid >> 6;

  floatx4 acc[2][4];
#pragma unroll
  for (int i = 0; i < 2; i++)
#pragma unroll
    for (int j = 0; j < 4; j++) acc[i][j] = (floatx4){0.f, 0.f, 0.f, 0.f};

  int arow = tid >> 1, ahalf = tid & 1;   // A: 128 rows x 64 bf16, 64 B/thread
  int brow = tid >> 2, bq = tid & 3;      // B: 64 rows x 64, 16 elems/thread
  int gnb = n0 + brow; if (gnb > N - 1) gnb = N - 1;

  const __bf16* abase = Abf + (size_t)arow * Kpitch + Koff + ahalf * 32;
  const float*  bfb = (const float*)Bsrc + (size_t)gnb * Kpitch + Koff + bq * 16;
  const __bf16* bhb = (const __bf16*)Bsrc + (size_t)gnb * Kpitch + Koff + bq * 16;

  uint4 ra[4];
  float4 rbf[4];
  uint4 rbh[2];
  {
    const uint4* s = (const uint4*)abase;
    ra[0] = s[0]; ra[1] = s[1]; ra[2] = s[2]; ra[3] = s[3];
    if (BF32) { const float4* t = (const float4*)bfb; rbf[0] = t[0]; rbf[1] = t[1]; rbf[2] = t[2]; rbf[3] = t[3]; }
    else      { const uint4* t = (const uint4*)bhb;  rbh[0] = t[0]; rbh[1] = t[1]; }
  }

  for (int k0 = 0; k0 < Klen; k0 += 64) {
    __syncthreads();
    { uint4* d = (uint4*)&As[arow][ahalf * 32]; d[0] = ra[0]; d[1] = ra[1]; d[2] = ra[2]; d[3] = ra[3]; }
    if (BF32) {
      uint4 o0, o1;
      o0.x = f2bf2(rbf[0].x, rbf[0].y); o0.y = f2bf2(rbf[0].z, rbf[0].w);
      o0.z = f2bf2(rbf[1].x, rbf[1].y); o0.w = f2bf2(rbf[1].z, rbf[1].w);
      o1.x = f2bf2(rbf[2].x, rbf[2].y); o1.y = f2bf2(rbf[2].z, rbf[2].w);
      o1.z = f2bf2(rbf[3].x, rbf[3].y); o1.w = f2bf2(rbf[3].z, rbf[3].w);
      uint4* d = (uint4*)&Bs[brow][bq * 16]; d[0] = o0; d[1] = o1;
    } else {
      uint4* d = (uint4*)&Bs[brow][bq * 16]; d[0] = rbh[0]; d[1] = rbh[1];
    }
    if (k0 + 64 < Klen) {
      const uint4* s = (const uint4*)(abase + k0 + 64);
      ra[0] = s[0]; ra[1] = s[1]; ra[2] = s[2]; ra[3] = s[3];
      if (BF32) { const float4* t = (const float4*)(bfb + k0 + 64); rbf[0] = t[0]; rbf[1] = t[1]; rbf[2] = t[2]; rbf[3] = t[3]; }
      else      { const uint4* t = (const uint4*)(bhb + k0 + 64);  rbh[0] = t[0]; rbh[1] = t[1]; }
    }
    __syncthreads();
#pragma unroll
    for (int kk = 0; kk < 64; kk += 32) {
      int kbase = kk + (lane >> 4) * 8;
      bf16x8 a0 = *(const bf16x8*)&As[wid * 32 + (lane & 15)][kbase];
      bf16x8 a1 = *(const bf16x8*)&As[wid * 32 + 16 + (lane & 15)][kbase];
      bf16x8 bfr[4];
#pragma unroll
      for (int j = 0; j < 4; j++) bfr[j] = *(const bf16x8*)&Bs[j * 16 + (lane & 15)][kbase];
#pragma unroll
      for (int j = 0; j < 4; j++) {
        acc[0][j] = __builtin_amdgcn_mfma_f32_16x16x32_bf16(a0, bfr[j], acc[0][j], 0, 0, 0);
        acc[1][j] = __builtin_amdgcn_mfma_f32_16x16x32_bf16(a1, bfr[j], acc[1][j], 0, 0, 0);
      }
    }
  }
  // C/D layout: col=lane&15, row=(lane>>4)*4+r  [m89/m91]
  int cn = lane & 15, cq = lane >> 4;
#pragma unroll
  for (int i = 0; i < 2; i++)
#pragma unroll
    for (int j = 0; j < 4; j++)
#pragma unroll
      for (int r = 0; r < 4; r++) {
        int row = wid * 32 + i * 16 + cq * 4 + r;
        int col = n0 + j * 16 + cn;
        if (col < N) {
          float v = acc[i][j][r];
          if (bias) v += bias[col];
          C[(size_t)row * ldc + col] = v;
        }
      }
  if (STATS) {
#pragma unroll
    for (int i = 0; i < 2; i++)
#pragma unroll
      for (int r = 0; r < 4; r++) {
        int row = wid * 32 + i * 16 + cq * 4 + r;
        float v[4]; float mx = -1e30f;
#pragma unroll
        for (int j = 0; j < 4; j++) {
          int col = n0 + j * 16 + cn;
          float x = acc[i][j][r] + bias[col < N ? col : N - 1];
          v[j] = (col < N) ? x : -1e30f;
          mx = fmaxf(mx, v[j]);
        }
#pragma unroll
        for (int mk = 1; mk <= 8; mk <<= 1) mx = fmaxf(mx, __shfl_xor(mx, mk, 64));
        float s = 0.f;
#pragma unroll
        for (int j = 0; j < 4; j++) s += (v[j] > -1e29f) ? __expf(v[j] - mx) : 0.f;
#pragma unroll
        for (int mk = 1; mk <= 8; mk <<= 1) s += __shfl_xor(s, mk, 64);
        if (cn == 0) mspart[(size_t)row * MSP_PITCH + cb] = make_float2(mx, s);
      }
  }
}

// gates GEMM, split-K x2: blocks [kh*32 + nb]
__global__ __launch_bounds__(256) void gates_gemm(
    const __bf16* __restrict__ Abuf, const __bf16* __restrict__ Wcat,
    float* __restrict__ g0, float* __restrict__ g1) {
  __shared__ __bf16 As[128][72];
  __shared__ __bf16 Bs[64][72];
  int bx = blockIdx.x;
  int kh = bx >> 5, nb = bx & 31;
  gemm64_body<0, 0>(As, Bs, Abuf, Wcat, nullptr, kh ? g1 : g0, nb * 64, FOURH,
                    kh * 384, 384, K_GATES, FOURH, nullptr, 0);
}

// ---------------- mega_gemm: R0's LDS-lockstep K-loop + coalesced ctile epilogue ----------------
// Big path (bx < NBIG): 128x64 C-tile of logits, K=512. K-loop identical to the
// proven 84us gemm64_body<BF32=1> (LDS double-stage, depth-1 reg prefetch).
// Epilogue: acc -> ctile (LDS, unioned over As/Bs so block LDS stays 32768 B ->
// 5 blocks/CU) -> one barrier -> full 256 B/row coalesced float4 stores (fixes
// the 88->29 MB WRITE_SIZE amplification of scalar C-writes, proven in R2/R3)
// + fused per-row softmax partials (mspart layout unchanged).
__global__ __launch_bounds__(256) void mega_gemm(
    const __bf16* __restrict__ h1b, const float* __restrict__ outW,
    const float* __restrict__ outb, float* __restrict__ logits, size_t lpitch,
    const __bf16* __restrict__ Wattn, const float* __restrict__ attnbc,
    float* __restrict__ decbuf, float2* __restrict__ mspart) {
  __shared__ __align__(16) char smem[32768];          // union: As+Bs (27648) / ctile (32768)
  __bf16 (*As)[72] = (__bf16(*)[72])smem;             // 128*72*2 = 18432
  __bf16 (*Bs)[72] = (__bf16(*)[72])(smem + 18432);   //  64*72*2 =  9216
  float  (*ctile)[64] = (float(*)[64])smem;           // 128*64*4 = 32768

  int bx = blockIdx.x;
  if (bx >= NBIG) {
    // attention projection blocks: unchanged scalar path (2 MB total writes)
    gemm64_body<0, 0>(As, Bs, h1b, Wattn, attnbc, decbuf, (bx - NBIG) * 64, 1024,
                      0, H_DIM, H_DIM, 1024, nullptr, 0);
    return;
  }

  int tid = threadIdx.x, lane = tid & 63, wid = tid >> 6;
  int n0 = bx * 64;

  floatx4 acc[2][4];
#pragma unroll
  for (int i = 0; i < 2; i++)
#pragma unroll
    for (int j = 0; j < 4; j++) acc[i][j] = (floatx4){0.f, 0.f, 0.f, 0.f};

  int arow = tid >> 1, ahalf = tid & 1;   // A: 128 rows x 64 bf16, 64 B/thread
  int brow = tid >> 2, bq = tid & 3;      // B: 64 rows x 64, 16 elems/thread
  int gnb = n0 + brow; if (gnb > V_DIM - 1) gnb = V_DIM - 1;

  const __bf16* abase = h1b + (size_t)arow * H_DIM + ahalf * 32;
  const float*  bfb   = outW + (size_t)gnb * H_DIM + bq * 16;

  uint4 ra[4];
  float4 rbf[4];
  {
    const uint4* s = (const uint4*)abase;
    ra[0] = s[0]; ra[1] = s[1]; ra[2] = s[2]; ra[3] = s[3];
    const float4* t = (const float4*)bfb;
    rbf[0] = t[0]; rbf[1] = t[1]; rbf[2] = t[2]; rbf[3] = t[3];
  }

  for (int k0 = 0; k0 < H_DIM; k0 += 64) {
    __syncthreads();
    { uint4* d = (uint4*)&As[arow][ahalf * 32]; d[0] = ra[0]; d[1] = ra[1]; d[2] = ra[2]; d[3] = ra[3]; }
    {
      uint4 o0, o1;
      o0.x = f2bf2(rbf[0].x, rbf[0].y); o0.y = f2bf2(rbf[0].z, rbf[0].w);
      o0.z = f2bf2(rbf[1].x, rbf[1].y); o0.w = f2bf2(rbf[1].z, rbf[1].w);
      o1.x = f2bf2(rbf[2].x, rbf[2].y); o1.y = f2bf2(rbf[2].z, rbf[2].w);
      o1.z = f2bf2(rbf[3].x, rbf[3].y); o1.w = f2bf2(rbf[3].z, rbf[3].w);
      uint4* d = (uint4*)&Bs[brow][bq * 16]; d[0] = o0; d[1] = o1;
    }
    if (k0 + 64 < H_DIM) {
      const uint4* s = (const uint4*)(abase + k0 + 64);
      ra[0] = s[0]; ra[1] = s[1]; ra[2] = s[2]; ra[3] = s[3];
      const float4* t = (const float4*)(bfb + k0 + 64);
      rbf[0] = t[0]; rbf[1] = t[1]; rbf[2] = t[2]; rbf[3] = t[3];
    }
    __syncthreads();
#pragma unroll
    for (int kk = 0; kk < 64; kk += 32) {
      int kbase = kk + (lane >> 4) * 8;
      bf16x8 a0 = *(const bf16x8*)&As[wid * 32 + (lane & 15)][kbase];
      bf16x8 a1 = *(const bf16x8*)&As[wid * 32 + 16 + (lane & 15)][kbase];
      bf16x8 bfr[4];
#pragma unroll
      for (int j = 0; j < 4; j++) bfr[j] = *(const bf16x8*)&Bs[j * 16 + (lane & 15)][kbase];
#pragma unroll
      for (int j = 0; j < 4; j++) {
        acc[0][j] = __builtin_amdgcn_mfma_f32_16x16x32_bf16(a0, bfr[j], acc[0][j], 0, 0, 0);
        acc[1][j] = __builtin_amdgcn_mfma_f32_16x16x32_bf16(a1, bfr[j], acc[1][j], 0, 0, 0);
      }
    }
  }

  // ---- epilogue: acc -> ctile (smem reused; barrier ensures As/Bs reads done) ----
  __syncthreads();
  {
    int cn = lane & 15, cq = lane >> 4;
#pragma unroll
    for (int i = 0; i < 2; i++)
#pragma unroll
      for (int j = 0; j < 4; j++)
#pragma unroll
        for (int r = 0; r < 4; r++)
          ctile[wid * 32 + i * 16 + cq * 4 + r][j * 16 + cn] = acc[i][j][r];
  }
  __syncthreads();

  // coalesced pass: thread (rr,c16); 16 lanes hold a full 64-col row
  int rr = tid >> 4, c16 = tid & 15;
  int c4 = c16 * 4;
  int col = n0 + c4;
  // bias (outb) for this thread's 4 columns, clamped on the last partial block
  float b0, b1, b2, b3;
  if (n0 + 64 <= V_DIM) {
    float4 bb = *(const float4*)(outb + col);
    b0 = bb.x; b1 = bb.y; b2 = bb.z; b3 = bb.w;
  } else {
    b0 = (col + 0 < V_DIM) ? outb[col + 0] : 0.f;
    b1 = (col + 1 < V_DIM) ? outb[col + 1] : 0.f;
    b2 = (col + 2 < V_DIM) ? outb[col + 2] : 0.f;
    b3 = (col + 3 < V_DIM) ? outb[col + 3] : 0.f;
  }
#pragma unroll
  for (int p = 0; p < 8; ++p) {
    int row = p * 16 + rr;
    floatx4 v = *(const floatx4*)&ctile[row][c4];
    v[0] += b0; v[1] += b1; v[2] += b2; v[3] += b3;
    // softmax partials over this block's valid cols
    float v0 = (col + 0 < V_DIM) ? v[0] : -1e30f;
    float v1 = (col + 1 < V_DIM) ? v[1] : -1e30f;
    float v2 = (col + 2 < V_DIM) ? v[2] : -1e30f;
    float v3 = (col + 3 < V_DIM) ? v[3] : -1e30f;
    float mx = fmaxf(fmaxf(v0, v1), fmaxf(v2, v3));
#pragma unroll
    for (int mk = 1; mk <= 8; mk <<= 1) mx = fmaxf(mx, __shfl_xor(mx, mk, 64));
    float sum = __expf(v0 - mx) + __expf(v1 - mx) + __expf(v2 - mx) + __expf(v3 - mx);
#pragma unroll
    for (int mk = 1; mk <= 8; mk <<= 1) sum += __shfl_xor(sum, mk, 64);
    if (c16 == 0) mspart[(size_t)row * MSP_PITCH + bx] = make_float2(mx, sum);
    if (col + 4 <= V_DIM) {
      float* dst = logits + (size_t)row * lpitch + col;
      if ((lpitch & 3) == 0) {
        *(floatx4*)dst = v;
      } else {
        *(floatx2*)dst = (floatx2){v[0], v[1]};
        *(floatx2*)(dst + 2) = (floatx2){v[2], v[3]};
      }
    }
  }
}

// ---------------- LSTM elementwise (sums the two split-K halves) ----------------
__global__ __launch_bounds__(256) void lstm_kernel(
    const float* __restrict__ gA, const float* __restrict__ gB,
    const float* __restrict__ b_ih, const float* __restrict__ b_hh,
    const float* __restrict__ c0,
    float* __restrict__ h1_out, float* __restrict__ c1_out, __bf16* __restrict__ h1b) {
  int idx = blockIdx.x * 256 + threadIdx.x;
  int b = idx >> 9, j = idx & 511;
  const float* ga = gA + b * FOURH;
  const float* gb = gB + b * FOURH;
  float iv = ga[j]        + gb[j]        + b_ih[j]        + b_hh[j];
  float fv = ga[512 + j]  + gb[512 + j]  + b_ih[512 + j]  + b_hh[512 + j];
  float gv = ga[1024 + j] + gb[1024 + j] + b_ih[1024 + j] + b_hh[1024 + j];
  float ov = ga[1536 + j] + gb[1536 + j] + b_ih[1536 + j] + b_hh[1536 + j];
  float c1 = sigm(fv) * c0[idx] + sigm(iv) * tanhf(gv);
  float h1 = sigm(ov) * tanhf(c1);
  h1_out[idx] = h1;
  c1_out[idx] = c1;
  h1b[idx] = (__bf16)h1;
}

// ---------------- flash attention (1024 blocks) ----------------
__global__ __launch_bounds__(256) void flash_kernel(
    const float* __restrict__ enc, const float* __restrict__ cenc,
    const float* __restrict__ decbuf, float* __restrict__ opart,
    float2* __restrict__ mlb, float* __restrict__ rawsc) {
  __shared__ float so[4][512];
  __shared__ float sml[4][2];
  int g = blockIdx.x;
  int b = g & 127;
  int cc = g >> 7;               // 0..7
  int which = cc >> 2, chunk = cc & 3;
  int tchunk = which ? 50 : 64;
  int t0 = chunk * tchunk;
  const float* src = which ? (cenc + (size_t)b * T_CTX * H_DIM) : (enc + (size_t)b * T_ENC * H_DIM);
  const float* decp = decbuf + b * 1024 + which * 512;
  int tid = threadIdx.x, lane = tid & 63, wid = tid >> 6;
  float4 d0 = *(const float4*)(decp + lane * 8);
  float4 d1 = *(const float4*)(decp + lane * 8 + 4);
  float m = -1e30f, l = 0.f;
  float4 o0 = {0.f, 0.f, 0.f, 0.f}, o1 = {0.f, 0.f, 0.f, 0.f};
  for (int t = t0 + wid; t < t0 + tchunk; t += 4) {
    const float* row = src + (size_t)t * H_DIM + lane * 8;
    float4 r0 = *(const float4*)row;
    float4 r1 = *(const float4*)(row + 4);
    float p = r0.x * d0.x + r0.y * d0.y + r0.z * d0.z + r0.w * d0.w +
              r1.x * d1.x + r1.y * d1.y + r1.z * d1.z + r1.w * d1.w;
    p = wave_sum(p);
    if (which && lane == 0) rawsc[b * T_CTX + t] = p;
    float mn = fmaxf(m, p);
    float sc = __expf(m - mn);
    float e  = __expf(p - mn);
    l = l * sc + e;
    o0.x = o0.x * sc + e * r0.x; o0.y = o0.y * sc + e * r0.y;
    o0.z = o0.z * sc + e * r0.z; o0.w = o0.w * sc + e * r0.w;
    o1.x = o1.x * sc + e * r1.x; o1.y = o1.y * sc + e * r1.y;
    o1.z = o1.z * sc + e * r1.z; o1.w = o1.w * sc + e * r1.w;
    m = mn;
  }
  *(float4*)&so[wid][lane * 8]     = o0;
  *(float4*)&so[wid][lane * 8 + 4] = o1;
  if (lane == 0) { sml[wid][0] = m; sml[wid][1] = l; }
  __syncthreads();
  float M = fmaxf(fmaxf(sml[0][0], sml[1][0]), fmaxf(sml[2][0], sml[3][0]));
  float w0 = __expf(sml[0][0] - M), w1 = __expf(sml[1][0] - M);
  float w2 = __expf(sml[2][0] - M), w3 = __expf(sml[3][0] - M);
  float L = w0 * sml[0][1] + w1 * sml[1][1] + w2 * sml[2][1] + w3 * sml[3][1];
  int h = tid, h2 = tid + 256;
  float O0 = w0 * so[0][h]  + w1 * so[1][h]  + w2 * so[2][h]  + w3 * so[3][h];
  float O1 = w0 * so[0][h2] + w1 * so[1][h2] + w2 * so[2][h2] + w3 * so[3][h2];
  opart[(size_t)g * 512 + h]  = O0;
  opart[(size_t)g * 512 + h2] = O1;
  if (tid == 0) mlb[g] = make_float2(M, L);
}

// ---------------- final: combine everything + write logp ----------------
__global__ __launch_bounds__(256) void final_kernel(
    const float* __restrict__ logits, size_t lpitch,
    float* __restrict__ out, const int* __restrict__ ctx_inp,
    const float* __restrict__ rawsc, const float2* __restrict__ mlb,
    const float2* __restrict__ mspart, const float* __restrict__ opart,
    const float* __restrict__ h1f, const float* __restrict__ embf,
    const float* __restrict__ genW, const float* __restrict__ genb,
    const float* __restrict__ sigb) {
  __shared__ float pc[VCHUNK];
  __shared__ float sm[256], ss[256];
  __shared__ float red8[8];
  int bx = blockIdx.x;           // c*128 + b
  int b = bx & 127, c = bx >> 7;
  int tid = threadIdx.x, lane = tid & 63, wid = tid >> 6;
  int cidx = (tid < T_CTX) ? ctx_inp[b * T_CTX + tid] : 0;

  // attention chunk-combine weights
  float2 e0 = mlb[b], e1 = mlb[128 + b], e2 = mlb[256 + b], e3 = mlb[384 + b];        // which=0
  float2 f0 = mlb[512 + b], f1 = mlb[640 + b], f2 = mlb[768 + b], f3 = mlb[896 + b];  // which=1
  float M0 = fmaxf(fmaxf(e0.x, e1.x), fmaxf(e2.x, e3.x));
  float a0 = __expf(e0.x - M0), a1 = __expf(e1.x - M0), a2 = __expf(e2.x - M0), a3 = __expf(e3.x - M0);
  float L0 = a0 * e0.y + a1 * e1.y + a2 * e2.y + a3 * e3.y;
  float M1 = fmaxf(fmaxf(f0.x, f1.x), fmaxf(f2.x, f3.x));
  float c0_ = __expf(f0.x - M1), c1_ = __expf(f1.x - M1), c2_ = __expf(f2.x - M1), c3_ = __expf(f3.x - M1);
  float L1 = c0_ * f0.y + c1_ * f1.y + c2_ * f2.y + c3_ * f3.y;

  // p_gen dot: feats = [ctx, cctx, h1, emb] . genW
  float acc = 0.f;
  for (int j = tid; j < 1792; j += 256) {
    float x;
    if (j < 1024) {
      int which = j >> 9, h = j & 511;
      const float* op = opart + ((size_t)(which * 512 + b) * 512) + h;
      if (which == 0)
        x = (a0 * op[0] + a1 * op[128 * 512] + a2 * op[256 * 512] + a3 * op[384 * 512]) / L0;
      else
        x = (c0_ * op[0] + c1_ * op[128 * 512] + c2_ * op[256 * 512] + c3_ * op[384 * 512]) / L1;
    } else if (j < 1536) x = h1f[b * 512 + j - 1024];
    else x = embf[b * 256 + j - 1536];
    acc += x * genW[j];
  }
  float cnt = (tid < T_CTX && cidx > 0) ? 1.f : 0.f;
  acc = wave_sum(acc); cnt = wave_sum(cnt);
  if (lane == 0) { red8[wid] = acc; red8[4 + wid] = cnt; }

  // row softmax stats from 782 per-block partials
  float m = -1e30f, s = 0.f;
  for (int cb = tid; cb < NBIG; cb += 256) {
    float2 p = mspart[(size_t)b * MSP_PITCH + cb];
    float mo = fmaxf(m, p.x);
    s = s * __expf(m - mo) + p.y * __expf(p.x - mo);
    m = mo;
  }
  sm[tid] = m; ss[tid] = s;
#pragma unroll
  for (int k = 0; k < 8; k++) pc[tid * 8 + k] = 0.f;
  __syncthreads();
  for (int st = 128; st; st >>= 1) {
    if (tid < st) {
      float m2 = sm[tid + st], s2 = ss[tid + st];
      float mo = fmaxf(sm[tid], m2);
      ss[tid] = ss[tid] * __expf(sm[tid] - mo) + s2 * __expf(m2 - mo);
      sm[tid] = mo;
    }
    __syncthreads();
  }
  float rm = sm[0], rs = ss[0];
  float pg;
  {
    float a = red8[0] + red8[1] + red8[2] + red8[3];
    float cn = red8[4] + red8[5] + red8[6] + red8[7];
    pg = sigm(a + genb[0] + sigb[0]);
    if (cn == 0.f) pg = 1.0f;
  }
  int v0c = c * VCHUNK;
  if (tid < T_CTX) {
    int rel = cidx - v0c;
    if (rel >= 0 && rel < VCHUNK) {
      float val = __expf(rawsc[b * T_CTX + tid] - M1) / L1;
      atomicAdd(&pc[rel], val);
    }
  }
  __syncthreads();
  float inv = 1.0f / rs, pc1 = 1.0f - pg;
  const float* rowsrc = logits + (size_t)b * lpitch;
  float* rowdst = out + (size_t)b * VEXT;
  int li0 = tid * 8;
#pragma unroll
  for (int k = 0; k < 4; k++) {
    int li = li0 + 2 * k;
    int v = v0c + li;
    float2 x = *(const float2*)(rowsrc + v);   // in-bounds of buffer; garbage past V_DIM guarded below
    float pv0 = (v < V_DIM)     ? __expf(x.x - rm) * inv : 0.f;
    float pv1 = (v + 1 < V_DIM) ? __expf(x.y - rm) * inv : 0.f;
    float r0 = __logf(fmaxf(pg * pv0 + pc1 * pc[li],     1e-10f));
    float r1 = __logf(fmaxf(pg * pv1 + pc1 * pc[li + 1], 1e-10f));
    if (v + 1 < VEXT)      *(float2*)(rowdst + v) = make_float2(r0, r1);
    else if (v < VEXT)     rowdst[v] = r0;
  }
}

extern "C" void kernel_launch(void* const* d_in, const int* in_sizes, int n_in,
                              void* d_out, int out_size, void* d_ws, size_t ws_size,
                              hipStream_t stream) {
  const int*   input   = (const int*)d_in[0];
  const float* h0      = (const float*)d_in[1];
  const float* c0      = (const float*)d_in[2];
  const float* enc     = (const float*)d_in[3];
  const float* cenc    = (const float*)d_in[4];
  const int*   ctx_inp = (const int*)d_in[5];
  const float* embT    = (const float*)d_in[6];
  const float* W_ih    = (const float*)d_in[7];
  const float* W_hh    = (const float*)d_in[8];
  const float* b_ih    = (const float*)d_in[9];
  const float* b_hh    = (const float*)d_in[10];
  const float* attnW   = (const float*)d_in[11];
  const float* attnb   = (const float*)d_in[12];
  const float* cattnW  = (const float*)d_in[13];
  const float* cattnb  = (const float*)d_in[14];
  const float* genW    = (const float*)d_in[15];
  const float* genb    = (const float*)d_in[16];
  const float* sigb    = (const float*)d_in[17];
  const float* outW    = (const float*)d_in[18];
  const float* outb    = (const float*)d_in[19];

  char* ws = (char*)d_ws;
  __bf16* Wcat   = (__bf16*)(ws + 0);            // 3145728
  __bf16* Wattn  = (__bf16*)(ws + 3145728);      // 1048576 -> 4194304
  float*  attnbc = (float*)(ws + 4194304);       // 4096    -> 4198400
  __bf16* Abuf   = (__bf16*)(ws + 4198400);      // 196608  -> 4395008
  float*  embf   = (float*)(ws + 4395008);       // 131072  -> 4526080
  float*  gates  = (float*)(ws + 4526080);       // 1048576 -> 5574656
  float*  gates2 = (float*)(ws + 5574656);       // 1048576 -> 6623232
  __bf16* h1b    = (__bf16*)(ws + 6623232);      // 131072  -> 6754304
  float*  decbuf = (float*)(ws + 6754304);       // 524288  -> 7278592
  float*  opart  = (float*)(ws + 7278592);       // 2097152 -> 9375744
  float2* mlb    = (float2*)(ws + 9375744);      // 8192    -> 9383936
  float*  rawsc  = (float*)(ws + 9383936);       // 102400  -> 9486336
  float2* mspart = (float2*)(ws + 9486336);      // 128*784*8 = 802816 -> 10289152
  const size_t logits_off = 10289152;
  const size_t LPITCH_AL = 50176;                // 64B-aligned row pitch

  float* outF = (float*)d_out;
  bool padded = ws_size >= logits_off + (size_t)BB * LPITCH_AL * 4;
  float* logits = padded ? (float*)(ws + logits_off) : outF;
  size_t lpitch = padded ? LPITCH_AL : (size_t)VEXT;

  float* h1_out = outF + OUT_H1_OFF;
  float* c1_out = outF + OUT_C1_OFF;

  prep_all<<<2176, 256, 0, stream>>>(W_ih, W_hh, attnW, cattnW, attnb, cattnb,
                                     input, embT, h0, Wcat, Wattn, attnbc, Abuf, embf);
  gates_gemm<<<64, 256, 0, stream>>>(Abuf, Wcat, gates, gates2);
  lstm_kernel<<<256, 256, 0, stream>>>(gates, gates2, b_ih, b_hh, c0, h1_out, c1_out, h1b);
  mega_gemm<<<NBIG + 16, 256, 0, stream>>>(h1b, outW, outb, logits, lpitch,
                                           Wattn, attnbc, decbuf, mspart);
  flash_kernel<<<1024, 256, 0, stream>>>(enc, cenc, decbuf, opart, mlb, rawsc);
  final_kernel<<<NCHUNK * 128, 256, 0, stream>>>(logits, lpitch, outF, ctx_inp, rawsc, mlb,
                                                 mspart, opart, h1_out, embf, genW, genb, sigb);
}

// Round 5
// 388.331 us; speedup vs baseline: 1.0386x; 1.0024x over previous
//
#include <hip/hip_runtime.h>
#include <hip/hip_bf16.h>

// Problem dims (fixed by setup_inputs)
#define BB 128
#define T_ENC 256
#define T_CTX 200
#define E_DIM 256
#define H_DIM 512
#define V_DIM 50000
#define N_OOV 50
#define VEXT  50050
#define FOURH 2048
#define K_GATES 768   // E + H
#define LOGP_SZ (BB * VEXT)          // 6406400
#define OUT_H1_OFF LOGP_SZ
#define OUT_C1_OFF (LOGP_SZ + BB * H_DIM)
#define VCHUNK 2048
#define NCHUNK 25     // 25*2048 = 51200 >= VEXT
#define NBIG 782      // ceil(50000/64)
#define MSP_PITCH 784 // padded 782

typedef __bf16 bf16x8 __attribute__((ext_vector_type(8)));
typedef float  floatx4 __attribute__((ext_vector_type(4)));
typedef float  floatx2 __attribute__((ext_vector_type(2)));

__device__ __forceinline__ float wave_sum(float v) {
#pragma unroll
  for (int m = 32; m > 0; m >>= 1) v += __shfl_xor(v, m, 64);
  return v;
}

__device__ __forceinline__ float sigm(float x) { return 1.0f / (1.0f + __expf(-x)); }

// pack 2 fp32 -> packed bf16x2 (RNE)
__device__ __forceinline__ unsigned f2bf2(float a, float b) {
  unsigned ua = __float_as_uint(a), ub = __float_as_uint(b);
  ua = (ua + 0x7FFFu + ((ua >> 16) & 1u)) >> 16;
  ub = (ub + 0x7FFFu + ((ub >> 16) & 1u)) & 0xFFFF0000u;
  return ua | ub;
}

// ---------------- prep: weights->bf16 + A matrix, one launch ----------------
__global__ __launch_bounds__(256) void prep_all(
    const float* __restrict__ W_ih, const float* __restrict__ W_hh,
    const float* __restrict__ attnW, const float* __restrict__ cattnW,
    const float* __restrict__ attnb, const float* __restrict__ cattnb,
    const int* __restrict__ input, const float* __restrict__ embT,
    const float* __restrict__ h0,
    __bf16* __restrict__ Wcat, __bf16* __restrict__ Wattn, float* __restrict__ attnbc,
    __bf16* __restrict__ Abuf, float* __restrict__ embf) {
  int n = blockIdx.x, tid = threadIdx.x;
  if (n < 2048) {
    unsigned* wr = (unsigned*)(Wcat + (size_t)n * K_GATES);
    for (int idx = tid; idx < 384; idx += 256) {
      int e0 = idx * 2;
      float2 x = (e0 < 256) ? *(const float2*)(W_ih + (size_t)n * E_DIM + e0)
                            : *(const float2*)(W_hh + (size_t)n * H_DIM + e0 - 256);
      wr[idx] = f2bf2(x.x, x.y);
    }
    if (n < 1024) {
      const float* src = (n < 512) ? (attnW + (size_t)n * H_DIM) : (cattnW + (size_t)(n - 512) * H_DIM);
      unsigned* wa = (unsigned*)(Wattn + (size_t)n * H_DIM);
      float2 x = *(const float2*)(src + tid * 2);
      wa[tid] = f2bf2(x.x, x.y);
    }
    if (n < 4) {
      int i = n * 256 + tid;
      attnbc[i] = (i < 512) ? attnb[i] : cattnb[i - 512];
    }
  } else {
    int b = n - 2048;
    int tok = input[b];
    unsigned* ar = (unsigned*)(Abuf + (size_t)b * K_GATES);
    for (int idx = tid; idx < 384; idx += 256) {
      int e0 = idx * 2;
      float2 x;
      if (e0 < 256) {
        x = *(const float2*)(embT + (size_t)tok * E_DIM + e0);
        *(float2*)(embf + b * E_DIM + e0) = x;
      } else {
        x = *(const float2*)(h0 + (size_t)b * H_DIM + e0 - 256);
      }
      ar[idx] = f2bf2(x.x, x.y);
    }
  }
}

// ---------------- GEMM body (LDS lockstep) — used by gates_gemm + attn path ----------------
template <int BF32, int STATS>
__device__ __forceinline__ void gemm64_body(
    __bf16 (* __restrict__ As)[72], __bf16 (* __restrict__ Bs)[72],
    const __bf16* __restrict__ Abf, const void* __restrict__ Bsrc,
    const float* __restrict__ bias, float* __restrict__ C,
    int n0, int N, int Koff, int Klen, int Kpitch, size_t ldc,
    float2* __restrict__ mspart, int cb) {
  int tid = threadIdx.x, lane = tid & 63, wid = tid >> 6;

  floatx4 acc[2][4];
#pragma unroll
  for (int i = 0; i < 2; i++)
#pragma unroll
    for (int j = 0; j < 4; j++) acc[i][j] = (floatx4){0.f, 0.f, 0.f, 0.f};

  int arow = tid >> 1, ahalf = tid & 1;   // A: 128 rows x 64 bf16, 64 B/thread
  int brow = tid >> 2, bq = tid & 3;      // B: 64 rows x 64, 16 elems/thread
  int gnb = n0 + brow; if (gnb > N - 1) gnb = N - 1;

  const __bf16* abase = Abf + (size_t)arow * Kpitch + Koff + ahalf * 32;
  const float*  bfb = (const float*)Bsrc + (size_t)gnb * Kpitch + Koff + bq * 16;
  const __bf16* bhb = (const __bf16*)Bsrc + (size_t)gnb * Kpitch + Koff + bq * 16;

  uint4 ra[4];
  float4 rbf[4];
  uint4 rbh[2];
  {
    const uint4* s = (const uint4*)abase;
    ra[0] = s[0]; ra[1] = s[1]; ra[2] = s[2]; ra[3] = s[3];
    if (BF32) { const float4* t = (const float4*)bfb; rbf[0] = t[0]; rbf[1] = t[1]; rbf[2] = t[2]; rbf[3] = t[3]; }
    else      { const uint4* t = (const uint4*)bhb;  rbh[0] = t[0]; rbh[1] = t[1]; }
  }

  for (int k0 = 0; k0 < Klen; k0 += 64) {
    __syncthreads();
    { uint4* d = (uint4*)&As[arow][ahalf * 32]; d[0] = ra[0]; d[1] = ra[1]; d[2] = ra[2]; d[3] = ra[3]; }
    if (BF32) {
      uint4 o0, o1;
      o0.x = f2bf2(rbf[0].x, rbf[0].y); o0.y = f2bf2(rbf[0].z, rbf[0].w);
      o0.z = f2bf2(rbf[1].x, rbf[1].y); o0.w = f2bf2(rbf[1].z, rbf[1].w);
      o1.x = f2bf2(rbf[2].x, rbf[2].y); o1.y = f2bf2(rbf[2].z, rbf[2].w);
      o1.z = f2bf2(rbf[3].x, rbf[3].y); o1.w = f2bf2(rbf[3].z, rbf[3].w);
      uint4* d = (uint4*)&Bs[brow][bq * 16]; d[0] = o0; d[1] = o1;
    } else {
      uint4* d = (uint4*)&Bs[brow][bq * 16]; d[0] = rbh[0]; d[1] = rbh[1];
    }
    if (k0 + 64 < Klen) {
      const uint4* s = (const uint4*)(abase + k0 + 64);
      ra[0] = s[0]; ra[1] = s[1]; ra[2] = s[2]; ra[3] = s[3];
      if (BF32) { const float4* t = (const float4*)(bfb + k0 + 64); rbf[0] = t[0]; rbf[1] = t[1]; rbf[2] = t[2]; rbf[3] = t[3]; }
      else      { const uint4* t = (const uint4*)(bhb + k0 + 64);  rbh[0] = t[0]; rbh[1] = t[1]; }
    }
    __syncthreads();
#pragma unroll
    for (int kk = 0; kk < 64; kk += 32) {
      int kbase = kk + (lane >> 4) * 8;
      bf16x8 a0 = *(const bf16x8*)&As[wid * 32 + (lane & 15)][kbase];
      bf16x8 a1 = *(const bf16x8*)&As[wid * 32 + 16 + (lane & 15)][kbase];
      bf16x8 bfr[4];
#pragma unroll
      for (int j = 0; j < 4; j++) bfr[j] = *(const bf16x8*)&Bs[j * 16 + (lane & 15)][kbase];
#pragma unroll
      for (int j = 0; j < 4; j++) {
        acc[0][j] = __builtin_amdgcn_mfma_f32_16x16x32_bf16(a0, bfr[j], acc[0][j], 0, 0, 0);
        acc[1][j] = __builtin_amdgcn_mfma_f32_16x16x32_bf16(a1, bfr[j], acc[1][j], 0, 0, 0);
      }
    }
  }
  // C/D layout: col=lane&15, row=(lane>>4)*4+r  [m89/m91]
  int cn = lane & 15, cq = lane >> 4;
#pragma unroll
  for (int i = 0; i < 2; i++)
#pragma unroll
    for (int j = 0; j < 4; j++)
#pragma unroll
      for (int r = 0; r < 4; r++) {
        int row = wid * 32 + i * 16 + cq * 4 + r;
        int col = n0 + j * 16 + cn;
        if (col < N) {
          float v = acc[i][j][r];
          if (bias) v += bias[col];
          C[(size_t)row * ldc + col] = v;
        }
      }
  if (STATS) {
#pragma unroll
    for (int i = 0; i < 2; i++)
#pragma unroll
      for (int r = 0; r < 4; r++) {
        int row = wid * 32 + i * 16 + cq * 4 + r;
        float v[4]; float mx = -1e30f;
#pragma unroll
        for (int j = 0; j < 4; j++) {
          int col = n0 + j * 16 + cn;
          float x = acc[i][j][r] + bias[col < N ? col : N - 1];
          v[j] = (col < N) ? x : -1e30f;
          mx = fmaxf(mx, v[j]);
        }
#pragma unroll
        for (int mk = 1; mk <= 8; mk <<= 1) mx = fmaxf(mx, __shfl_xor(mx, mk, 64));
        float s = 0.f;
#pragma unroll
        for (int j = 0; j < 4; j++) s += (v[j] > -1e29f) ? __expf(v[j] - mx) : 0.f;
#pragma unroll
        for (int mk = 1; mk <= 8; mk <<= 1) s += __shfl_xor(s, mk, 64);
        if (cn == 0) mspart[(size_t)row * MSP_PITCH + cb] = make_float2(mx, s);
      }
  }
}

// gates GEMM, split-K x2: blocks [kh*32 + nb]
// __launch_bounds__(256,4): 128-VGPR budget -> no scratch spill (default build
// chased 8-waves/EU occupancy it can't reach and spilled the pipeline regs).
__global__ __launch_bounds__(256, 4) void gates_gemm(
    const __bf16* __restrict__ Abuf, const __bf16* __restrict__ Wcat,
    float* __restrict__ g0, float* __restrict__ g1) {
  __shared__ __bf16 As[128][72];
  __shared__ __bf16 Bs[64][72];
  int bx = blockIdx.x;
  int kh = bx >> 5, nb = bx & 31;
  gemm64_body<0, 0>(As, Bs, Abuf, Wcat, nullptr, kh ? g1 : g0, nb * 64, FOURH,
                    kh * 384, 384, K_GATES, FOURH, nullptr, 0);
}

// ---------------- mega_gemm: LDS-lockstep K-loop + coalesced ctile epilogue ----------------
// __launch_bounds__(256,4): THE round-5 fix. R0/R4 builds allocated only 48-56
// VGPR (allocator chasing 8 waves/EU that LDS already forbids) and spilled the
// K-loop pipeline regs to scratch -> ~83 MB/iter of hidden global spill traffic
// (WRITE_SIZE 112 vs 29 MB clean) sitting in every slab's critical path.
// 128-VGPR budget holds acc(32)+ra(16)+rbf(16)+addressing live; LDS (34816 B,
// As/Bs unioned with padded ctile[128][68]) allows the same 4 blocks/CU.
__global__ __launch_bounds__(256, 4) void mega_gemm(
    const __bf16* __restrict__ h1b, const float* __restrict__ outW,
    const float* __restrict__ outb, float* __restrict__ logits, size_t lpitch,
    const __bf16* __restrict__ Wattn, const float* __restrict__ attnbc,
    float* __restrict__ decbuf, float2* __restrict__ mspart) {
  __shared__ __align__(16) char smem[34816];          // union: As+Bs (27648) / ctile (34816)
  __bf16 (*As)[72] = (__bf16(*)[72])smem;             // 128*72*2 = 18432
  __bf16 (*Bs)[72] = (__bf16(*)[72])(smem + 18432);   //  64*72*2 =  9216
  float  (*ctile)[68] = (float(*)[68])smem;           // 128*68*4 = 34816 (pad 68: bank spread)

  int bx = blockIdx.x;
  if (bx >= NBIG) {
    // attention projection blocks: unchanged scalar path (2 MB total writes)
    gemm64_body<0, 0>(As, Bs, h1b, Wattn, attnbc, decbuf, (bx - NBIG) * 64, 1024,
                      0, H_DIM, H_DIM, 1024, nullptr, 0);
    return;
  }

  int tid = threadIdx.x, lane = tid & 63, wid = tid >> 6;
  int n0 = bx * 64;

  floatx4 acc[2][4];
#pragma unroll
  for (int i = 0; i < 2; i++)
#pragma unroll
    for (int j = 0; j < 4; j++) acc[i][j] = (floatx4){0.f, 0.f, 0.f, 0.f};

  int arow = tid >> 1, ahalf = tid & 1;   // A: 128 rows x 64 bf16, 64 B/thread
  int brow = tid >> 2, bq = tid & 3;      // B: 64 rows x 64, 16 elems/thread
  int gnb = n0 + brow; if (gnb > V_DIM - 1) gnb = V_DIM - 1;

  const __bf16* abase = h1b + (size_t)arow * H_DIM + ahalf * 32;
  const float*  bfb   = outW + (size_t)gnb * H_DIM + bq * 16;

  uint4 ra[4];
  float4 rbf[4];
  {
    const uint4* s = (const uint4*)abase;
    ra[0] = s[0]; ra[1] = s[1]; ra[2] = s[2]; ra[3] = s[3];
    const float4* t = (const float4*)bfb;
    rbf[0] = t[0]; rbf[1] = t[1]; rbf[2] = t[2]; rbf[3] = t[3];
  }

  for (int k0 = 0; k0 < H_DIM; k0 += 64) {
    __syncthreads();
    { uint4* d = (uint4*)&As[arow][ahalf * 32]; d[0] = ra[0]; d[1] = ra[1]; d[2] = ra[2]; d[3] = ra[3]; }
    {
      uint4 o0, o1;
      o0.x = f2bf2(rbf[0].x, rbf[0].y); o0.y = f2bf2(rbf[0].z, rbf[0].w);
      o0.z = f2bf2(rbf[1].x, rbf[1].y); o0.w = f2bf2(rbf[1].z, rbf[1].w);
      o1.x = f2bf2(rbf[2].x, rbf[2].y); o1.y = f2bf2(rbf[2].z, rbf[2].w);
      o1.z = f2bf2(rbf[3].x, rbf[3].y); o1.w = f2bf2(rbf[3].z, rbf[3].w);
      uint4* d = (uint4*)&Bs[brow][bq * 16]; d[0] = o0; d[1] = o1;
    }
    if (k0 + 64 < H_DIM) {
      const uint4* s = (const uint4*)(abase + k0 + 64);
      ra[0] = s[0]; ra[1] = s[1]; ra[2] = s[2]; ra[3] = s[3];
      const float4* t = (const float4*)(bfb + k0 + 64);
      rbf[0] = t[0]; rbf[1] = t[1]; rbf[2] = t[2]; rbf[3] = t[3];
    }
    __syncthreads();
#pragma unroll
    for (int kk = 0; kk < 64; kk += 32) {
      int kbase = kk + (lane >> 4) * 8;
      bf16x8 a0 = *(const bf16x8*)&As[wid * 32 + (lane & 15)][kbase];
      bf16x8 a1 = *(const bf16x8*)&As[wid * 32 + 16 + (lane & 15)][kbase];
      bf16x8 bfr[4];
#pragma unroll
      for (int j = 0; j < 4; j++) bfr[j] = *(const bf16x8*)&Bs[j * 16 + (lane & 15)][kbase];
#pragma unroll
      for (int j = 0; j < 4; j++) {
        acc[0][j] = __builtin_amdgcn_mfma_f32_16x16x32_bf16(a0, bfr[j], acc[0][j], 0, 0, 0);
        acc[1][j] = __builtin_amdgcn_mfma_f32_16x16x32_bf16(a1, bfr[j], acc[1][j], 0, 0, 0);
      }
    }
  }

  // ---- epilogue: acc -> ctile (smem reused; barrier ensures As/Bs reads done) ----
  __syncthreads();
  {
    int cn = lane & 15, cq = lane >> 4;
#pragma unroll
    for (int i = 0; i < 2; i++)
#pragma unroll
      for (int j = 0; j < 4; j++)
#pragma unroll
        for (int r = 0; r < 4; r++)
          ctile[wid * 32 + i * 16 + cq * 4 + r][j * 16 + cn] = acc[i][j][r];
  }
  __syncthreads();

  // coalesced pass: thread (rr,c16); 16 lanes hold a full 64-col row
  int rr = tid >> 4, c16 = tid & 15;
  int c4 = c16 * 4;
  int col = n0 + c4;
  // bias (outb) for this thread's 4 columns, clamped on the last partial block
  float b0, b1, b2, b3;
  if (n0 + 64 <= V_DIM) {
    float4 bb = *(const float4*)(outb + col);
    b0 = bb.x; b1 = bb.y; b2 = bb.z; b3 = bb.w;
  } else {
    b0 = (col + 0 < V_DIM) ? outb[col + 0] : 0.f;
    b1 = (col + 1 < V_DIM) ? outb[col + 1] : 0.f;
    b2 = (col + 2 < V_DIM) ? outb[col + 2] : 0.f;
    b3 = (col + 3 < V_DIM) ? outb[col + 3] : 0.f;
  }
#pragma unroll
  for (int p = 0; p < 8; ++p) {
    int row = p * 16 + rr;
    floatx4 v = *(const floatx4*)&ctile[row][c4];
    v[0] += b0; v[1] += b1; v[2] += b2; v[3] += b3;
    // softmax partials over this block's valid cols
    float v0 = (col + 0 < V_DIM) ? v[0] : -1e30f;
    float v1 = (col + 1 < V_DIM) ? v[1] : -1e30f;
    float v2 = (col + 2 < V_DIM) ? v[2] : -1e30f;
    float v3 = (col + 3 < V_DIM) ? v[3] : -1e30f;
    float mx = fmaxf(fmaxf(v0, v1), fmaxf(v2, v3));
#pragma unroll
    for (int mk = 1; mk <= 8; mk <<= 1) mx = fmaxf(mx, __shfl_xor(mx, mk, 64));
    float sum = __expf(v0 - mx) + __expf(v1 - mx) + __expf(v2 - mx) + __expf(v3 - mx);
#pragma unroll
    for (int mk = 1; mk <= 8; mk <<= 1) sum += __shfl_xor(sum, mk, 64);
    if (c16 == 0) mspart[(size_t)row * MSP_PITCH + bx] = make_float2(mx, sum);
    if (col + 4 <= V_DIM) {
      float* dst = logits + (size_t)row * lpitch + col;
      if ((lpitch & 3) == 0) {
        *(floatx4*)dst = v;
      } else {
        *(floatx2*)dst = (floatx2){v[0], v[1]};
        *(floatx2*)(dst + 2) = (floatx2){v[2], v[3]};
      }
    }
  }
}

// ---------------- LSTM elementwise (sums the two split-K halves) ----------------
__global__ __launch_bounds__(256) void lstm_kernel(
    const float* __restrict__ gA, const float* __restrict__ gB,
    const float* __restrict__ b_ih, const float* __restrict__ b_hh,
    const float* __restrict__ c0,
    float* __restrict__ h1_out, float* __restrict__ c1_out, __bf16* __restrict__ h1b) {
  int idx = blockIdx.x * 256 + threadIdx.x;
  int b = idx >> 9, j = idx & 511;
  const float* ga = gA + b * FOURH;
  const float* gb = gB + b * FOURH;
  float iv = ga[j]        + gb[j]        + b_ih[j]        + b_hh[j];
  float fv = ga[512 + j]  + gb[512 + j]  + b_ih[512 + j]  + b_hh[512 + j];
  float gv = ga[1024 + j] + gb[1024 + j] + b_ih[1024 + j] + b_hh[1024 + j];
  float ov = ga[1536 + j] + gb[1536 + j] + b_ih[1536 + j] + b_hh[1536 + j];
  float c1 = sigm(fv) * c0[idx] + sigm(iv) * tanhf(gv);
  float h1 = sigm(ov) * tanhf(c1);
  h1_out[idx] = h1;
  c1_out[idx] = c1;
  h1b[idx] = (__bf16)h1;
}

// ---------------- flash attention (1024 blocks) ----------------
__global__ __launch_bounds__(256) void flash_kernel(
    const float* __restrict__ enc, const float* __restrict__ cenc,
    const float* __restrict__ decbuf, float* __restrict__ opart,
    float2* __restrict__ mlb, float* __restrict__ rawsc) {
  __shared__ float so[4][512];
  __shared__ float sml[4][2];
  int g = blockIdx.x;
  int b = g & 127;
  int cc = g >> 7;               // 0..7
  int which = cc >> 2, chunk = cc & 3;
  int tchunk = which ? 50 : 64;
  int t0 = chunk * tchunk;
  const float* src = which ? (cenc + (size_t)b * T_CTX * H_DIM) : (enc + (size_t)b * T_ENC * H_DIM);
  const float* decp = decbuf + b * 1024 + which * 512;
  int tid = threadIdx.x, lane = tid & 63, wid = tid >> 6;
  float4 d0 = *(const float4*)(decp + lane * 8);
  float4 d1 = *(const float4*)(decp + lane * 8 + 4);
  float m = -1e30f, l = 0.f;
  float4 o0 = {0.f, 0.f, 0.f, 0.f}, o1 = {0.f, 0.f, 0.f, 0.f};
  for (int t = t0 + wid; t < t0 + tchunk; t += 4) {
    const float* row = src + (size_t)t * H_DIM + lane * 8;
    float4 r0 = *(const float4*)row;
    float4 r1 = *(const float4*)(row + 4);
    float p = r0.x * d0.x + r0.y * d0.y + r0.z * d0.z + r0.w * d0.w +
              r1.x * d1.x + r1.y * d1.y + r1.z * d1.z + r1.w * d1.w;
    p = wave_sum(p);
    if (which && lane == 0) rawsc[b * T_CTX + t] = p;
    float mn = fmaxf(m, p);
    float sc = __expf(m - mn);
    float e  = __expf(p - mn);
    l = l * sc + e;
    o0.x = o0.x * sc + e * r0.x; o0.y = o0.y * sc + e * r0.y;
    o0.z = o0.z * sc + e * r0.z; o0.w = o0.w * sc + e * r0.w;
    o1.x = o1.x * sc + e * r1.x; o1.y = o1.y * sc + e * r1.y;
    o1.z = o1.z * sc + e * r1.z; o1.w = o1.w * sc + e * r1.w;
    m = mn;
  }
  *(float4*)&so[wid][lane * 8]     = o0;
  *(float4*)&so[wid][lane * 8 + 4] = o1;
  if (lane == 0) { sml[wid][0] = m; sml[wid][1] = l; }
  __syncthreads();
  float M = fmaxf(fmaxf(sml[0][0], sml[1][0]), fmaxf(sml[2][0], sml[3][0]));
  float w0 = __expf(sml[0][0] - M), w1 = __expf(sml[1][0] - M);
  float w2 = __expf(sml[2][0] - M), w3 = __expf(sml[3][0] - M);
  float L = w0 * sml[0][1] + w1 * sml[1][1] + w2 * sml[2][1] + w3 * sml[3][1];
  int h = tid, h2 = tid + 256;
  float O0 = w0 * so[0][h]  + w1 * so[1][h]  + w2 * so[2][h]  + w3 * so[3][h];
  float O1 = w0 * so[0][h2] + w1 * so[1][h2] + w2 * so[2][h2] + w3 * so[3][h2];
  opart[(size_t)g * 512 + h]  = O0;
  opart[(size_t)g * 512 + h2] = O1;
  if (tid == 0) mlb[g] = make_float2(M, L);
}

// ---------------- final: combine everything + write logp ----------------
__global__ __launch_bounds__(256) void final_kernel(
    const float* __restrict__ logits, size_t lpitch,
    float* __restrict__ out, const int* __restrict__ ctx_inp,
    const float* __restrict__ rawsc, const float2* __restrict__ mlb,
    const float2* __restrict__ mspart, const float* __restrict__ opart,
    const float* __restrict__ h1f, const float* __restrict__ embf,
    const float* __restrict__ genW, const float* __restrict__ genb,
    const float* __restrict__ sigb) {
  __shared__ float pc[VCHUNK];
  __shared__ float sm[256], ss[256];
  __shared__ float red8[8];
  int bx = blockIdx.x;           // c*128 + b
  int b = bx & 127, c = bx >> 7;
  int tid = threadIdx.x, lane = tid & 63, wid = tid >> 6;
  int cidx = (tid < T_CTX) ? ctx_inp[b * T_CTX + tid] : 0;

  // attention chunk-combine weights
  float2 e0 = mlb[b], e1 = mlb[128 + b], e2 = mlb[256 + b], e3 = mlb[384 + b];        // which=0
  float2 f0 = mlb[512 + b], f1 = mlb[640 + b], f2 = mlb[768 + b], f3 = mlb[896 + b];  // which=1
  float M0 = fmaxf(fmaxf(e0.x, e1.x), fmaxf(e2.x, e3.x));
  float a0 = __expf(e0.x - M0), a1 = __expf(e1.x - M0), a2 = __expf(e2.x - M0), a3 = __expf(e3.x - M0);
  float L0 = a0 * e0.y + a1 * e1.y + a2 * e2.y + a3 * e3.y;
  float M1 = fmaxf(fmaxf(f0.x, f1.x), fmaxf(f2.x, f3.x));
  float c0_ = __expf(f0.x - M1), c1_ = __expf(f1.x - M1), c2_ = __expf(f2.x - M1), c3_ = __expf(f3.x - M1);
  float L1 = c0_ * f0.y + c1_ * f1.y + c2_ * f2.y + c3_ * f3.y;

  // p_gen dot: feats = [ctx, cctx, h1, emb] . genW
  float acc = 0.f;
  for (int j = tid; j < 1792; j += 256) {
    float x;
    if (j < 1024) {
      int which = j >> 9, h = j & 511;
      const float* op = opart + ((size_t)(which * 512 + b) * 512) + h;
      if (which == 0)
        x = (a0 * op[0] + a1 * op[128 * 512] + a2 * op[256 * 512] + a3 * op[384 * 512]) / L0;
      else
        x = (c0_ * op[0] + c1_ * op[128 * 512] + c2_ * op[256 * 512] + c3_ * op[384 * 512]) / L1;
    } else if (j < 1536) x = h1f[b * 512 + j - 1024];
    else x = embf[b * 256 + j - 1536];
    acc += x * genW[j];
  }
  float cnt = (tid < T_CTX && cidx > 0) ? 1.f : 0.f;
  acc = wave_sum(acc); cnt = wave_sum(cnt);
  if (lane == 0) { red8[wid] = acc; red8[4 + wid] = cnt; }

  // row softmax stats from 782 per-block partials
  float m = -1e30f, s = 0.f;
  for (int cb = tid; cb < NBIG; cb += 256) {
    float2 p = mspart[(size_t)b * MSP_PITCH + cb];
    float mo = fmaxf(m, p.x);
    s = s * __expf(m - mo) + p.y * __expf(p.x - mo);
    m = mo;
  }
  sm[tid] = m; ss[tid] = s;
#pragma unroll
  for (int k = 0; k < 8; k++) pc[tid * 8 + k] = 0.f;
  __syncthreads();
  for (int st = 128; st; st >>= 1) {
    if (tid < st) {
      float m2 = sm[tid + st], s2 = ss[tid + st];
      float mo = fmaxf(sm[tid], m2);
      ss[tid] = ss[tid] * __expf(sm[tid] - mo) + s2 * __expf(m2 - mo);
      sm[tid] = mo;
    }
    __syncthreads();
  }
  float rm = sm[0], rs = ss[0];
  float pg;
  {
    float a = red8[0] + red8[1] + red8[2] + red8[3];
    float cn = red8[4] + red8[5] + red8[6] + red8[7];
    pg = sigm(a + genb[0] + sigb[0]);
    if (cn == 0.f) pg = 1.0f;
  }
  int v0c = c * VCHUNK;
  if (tid < T_CTX) {
    int rel = cidx - v0c;
    if (rel >= 0 && rel < VCHUNK) {
      float val = __expf(rawsc[b * T_CTX + tid] - M1) / L1;
      atomicAdd(&pc[rel], val);
    }
  }
  __syncthreads();
  float inv = 1.0f / rs, pc1 = 1.0f - pg;
  const float* rowsrc = logits + (size_t)b * lpitch;
  float* rowdst = out + (size_t)b * VEXT;
  int li0 = tid * 8;
#pragma unroll
  for (int k = 0; k < 4; k++) {
    int li = li0 + 2 * k;
    int v = v0c + li;
    float2 x = *(const float2*)(rowsrc + v);   // in-bounds of buffer; garbage past V_DIM guarded below
    float pv0 = (v < V_DIM)     ? __expf(x.x - rm) * inv : 0.f;
    float pv1 = (v + 1 < V_DIM) ? __expf(x.y - rm) * inv : 0.f;
    float r0 = __logf(fmaxf(pg * pv0 + pc1 * pc[li],     1e-10f));
    float r1 = __logf(fmaxf(pg * pv1 + pc1 * pc[li + 1], 1e-10f));
    if (v + 1 < VEXT)      *(float2*)(rowdst + v) = make_float2(r0, r1);
    else if (v < VEXT)     rowdst[v] = r0;
  }
}

extern "C" void kernel_launch(void* const* d_in, const int* in_sizes, int n_in,
                              void* d_out, int out_size, void* d_ws, size_t ws_size,
                              hipStream_t stream) {
  const int*   input   = (const int*)d_in[0];
  const float* h0      = (const float*)d_in[1];
  const float* c0      = (const float*)d_in[2];
  const float* enc     = (const float*)d_in[3];
  const float* cenc    = (const float*)d_in[4];
  const int*   ctx_inp = (const int*)d_in[5];
  const float* embT    = (const float*)d_in[6];
  const float* W_ih    = (const float*)d_in[7];
  const float* W_hh    = (const float*)d_in[8];
  const float* b_ih    = (const float*)d_in[9];
  const float* b_hh    = (const float*)d_in[10];
  const float* attnW   = (const float*)d_in[11];
  const float* attnb   = (const float*)d_in[12];
  const float* cattnW  = (const float*)d_in[13];
  const float* cattnb  = (const float*)d_in[14];
  const float* genW    = (const float*)d_in[15];
  const float* genb    = (const float*)d_in[16];
  const float* sigb    = (const float*)d_in[17];
  const float* outW    = (const float*)d_in[18];
  const float* outb    = (const float*)d_in[19];

  char* ws = (char*)d_ws;
  __bf16* Wcat   = (__bf16*)(ws + 0);            // 3145728
  __bf16* Wattn  = (__bf16*)(ws + 3145728);      // 1048576 -> 4194304
  float*  attnbc = (float*)(ws + 4194304);       // 4096    -> 4198400
  __bf16* Abuf   = (__bf16*)(ws + 4198400);      // 196608  -> 4395008
  float*  embf   = (float*)(ws + 4395008);       // 131072  -> 4526080
  float*  gates  = (float*)(ws + 4526080);       // 1048576 -> 5574656
  float*  gates2 = (float*)(ws + 5574656);       // 1048576 -> 6623232
  __bf16* h1b    = (__bf16*)(ws + 6623232);      // 131072  -> 6754304
  float*  decbuf = (float*)(ws + 6754304);       // 524288  -> 7278592
  float*  opart  = (float*)(ws + 7278592);       // 2097152 -> 9375744
  float2* mlb    = (float2*)(ws + 9375744);      // 8192    -> 9383936
  float*  rawsc  = (float*)(ws + 9383936);       // 102400  -> 9486336
  float2* mspart = (float2*)(ws + 9486336);      // 128*784*8 = 802816 -> 10289152
  const size_t logits_off = 10289152;
  const size_t LPITCH_AL = 50176;                // 64B-aligned row pitch

  float* outF = (float*)d_out;
  bool padded = ws_size >= logits_off + (size_t)BB * LPITCH_AL * 4;
  float* logits = padded ? (float*)(ws + logits_off) : outF;
  size_t lpitch = padded ? LPITCH_AL : (size_t)VEXT;

  float* h1_out = outF + OUT_H1_OFF;
  float* c1_out = outF + OUT_C1_OFF;

  prep_all<<<2176, 256, 0, stream>>>(W_ih, W_hh, attnW, cattnW, attnb, cattnb,
                                     input, embT, h0, Wcat, Wattn, attnbc, Abuf, embf);
  gates_gemm<<<64, 256, 0, stream>>>(Abuf, Wcat, gates, gates2);
  lstm_kernel<<<256, 256, 0, stream>>>(gates, gates2, b_ih, b_hh, c0, h1_out, c1_out, h1b);
  mega_gemm<<<NBIG + 16, 256, 0, stream>>>(h1b, outW, outb, logits, lpitch,
                                           Wattn, attnbc, decbuf, mspart);
  flash_kernel<<<1024, 256, 0, stream>>>(enc, cenc, decbuf, opart, mlb, rawsc);
  final_kernel<<<NCHUNK * 128, 256, 0, stream>>>(logits, lpitch, outF, ctx_inp, rawsc, mlb,
                                                 mspart, opart, h1_out, embf, genW, genb, sigb);
}